// Round 10
// baseline (3167.614 us; speedup 1.0000x reference)
//
#include <hip/hip_runtime.h>
#include <math.h>

typedef int i32x4 __attribute__((ext_vector_type(4)));
typedef float f32x4 __attribute__((ext_vector_type(4)));
typedef float f32x2 __attribute__((ext_vector_type(2)));

#define QMAXF 127.0f
#define EPSQ 1e-8f

__device__ __forceinline__ void gl_lds16(const void* g, void* l) {
  __builtin_amdgcn_global_load_lds(
      (const __attribute__((address_space(1))) unsigned int*)g,
      (__attribute__((address_space(3))) unsigned int*)l, 16, 0, 0);
}
__device__ __forceinline__ void gl_lds4(const void* g, void* l) {
  __builtin_amdgcn_global_load_lds(
      (const __attribute__((address_space(1))) unsigned int*)g,
      (__attribute__((address_space(3))) unsigned int*)l, 4, 0, 0);
}

// Group-of-128 symmetric int8 quant: fp32 in -> int8 q + transposed scales.
// Exact reference math in fp32 (max/127, maximum(.,eps), divide, rint, clip).
__global__ __launch_bounds__(256)
void qdq8(const float* __restrict__ in, char* __restrict__ q,
          float* __restrict__ sT, long n_groups, int gpr, int R) {
  long wid = (long)blockIdx.x * 4 + (threadIdx.x >> 6);
  if (wid >= n_groups) return;
  int lane = threadIdx.x & 63;
  long base = wid * 128 + lane * 2;
  f32x2 v = *(const f32x2*)(in + base);
  float m = fmaxf(fabsf(v.x), fabsf(v.y));
#pragma unroll
  for (int off = 32; off; off >>= 1) m = fmaxf(m, __shfl_xor(m, off));
  float s = fmaxf(m / QMAXF, EPSQ);
  int q0 = (int)fminf(fmaxf(rintf(v.x / s), -QMAXF), QMAXF);
  int q1 = (int)fminf(fmaxf(rintf(v.y / s), -QMAXF), QMAXF);
  *(unsigned short*)(q + base) =
      (unsigned short)((q0 & 0xff) | ((q1 & 0xff) << 8));
  if (lane == 0) {
    long row = wid / gpr;
    long gc = wid - row * gpr;
    sT[gc * (long)R + row] = s;
  }
}

// ---------------------------------------------------------------------------
// v10: large tile + reg-fit + 4 waves/SIMD.
// gu: 128x128 tile (r5 intensity), 512 thr / 8 waves (2wm x 4wn), per-wave
//     64 rows x 32 cols for BOTH dtypes -> acc = 64 f32, fits 128-reg budget
//     => no AGPR shuttle AND 4 waves/SIMD (2 indep blocks/CU).
// dn: 128x256 tile, 8 waves (2wm x 4wn), per-wave 64x64 single dtype.
// i-range processed in two halves (af liveness 16 regs; B-frags re-read --
// ds_read count/group unchanged vs r5). r5 skeleton: stage->sync->compute->
// sync, single-buffered LDS, G4 XOR swizzle both sides (verified r5),
// exact int32 MFMA per K-group (=128 = one quant group), fp32 rescale.
// ---------------------------------------------------------------------------

// Fused gate/up GEMM + SwiGLU + hidden group-quant (group = tile's 128 cols).
__global__ __launch_bounds__(512, 4)
void gemm_gu_i8(const char* __restrict__ Aq, const char* __restrict__ Bg,
                const char* __restrict__ Bu,
                const float* __restrict__ sAT, const float* __restrict__ sGT,
                const float* __restrict__ sUT,
                char* __restrict__ Hq, float* __restrict__ sHT,
                int M, int N, int K, int NBN) {
  __shared__ __align__(16) char sA[16384];   // 128 rows x 128 B
  __shared__ __align__(16) char sBG[16384];
  __shared__ __align__(16) char sBU[16384];
  __shared__ float sSa[128], sSg[128], sSu[128];
  __shared__ float rmx[4][128];
  __shared__ float rs[128];

  const int tid = threadIdx.x;
  const int lane = tid & 63;
  const int wid = tid >> 6;
  const int wm = wid >> 2, wn = wid & 3;
  const int wr = wm * 64, wc = wn * 32;
  const int l15 = lane & 15, l16 = lane >> 4;

  const int nwg = gridDim.x;
  const int wg = ((int)blockIdx.x & 7) * (nwg >> 3) + ((int)blockIdx.x >> 3);
  const long m0 = (long)(wg / NBN) * 128;
  const long n0 = (long)(wg % NBN) * 128;

  // staging: each 16KB tile = 1024 chunks; thread stages c = tid, tid+512
  // (rows rowS, rowS+64; row&7 invariant under +64 -> same swizzled offset).
  const long rowS = tid >> 3;
  const int offS = ((tid & 7) * 16) ^ ((int)(rowS & 7) << 4);
  const long kstr = 64L * K;
  const char* gA0 = Aq + (m0 + rowS) * K + offS;
  const char* gG0 = Bg + (n0 + rowS) * K + offS;
  const char* gU0 = Bu + (n0 + rowS) * K + offS;

  const int rdSwz = (l15 & 7) << 4;
  const int colK0 = (l16 * 16) ^ rdSwz;
  const int colK1 = (64 + l16 * 16) ^ rdSwz;

  f32x4 accg[4][2], accu[4][2];
#pragma unroll
  for (int i = 0; i < 4; i++)
#pragma unroll
    for (int j = 0; j < 2; j++) {
      accg[i][j] = (f32x4){0.f, 0.f, 0.f, 0.f};
      accu[i][j] = (f32x4){0.f, 0.f, 0.f, 0.f};
    }
  const i32x4 iz = {0, 0, 0, 0};
  const int KG = K >> 7;

  for (int g = 0; g < KG; ++g) {
    const long kb = (long)g << 7;
    gl_lds16(gA0 + kb, &sA[tid * 16]);
    gl_lds16(gA0 + kb + kstr, &sA[(tid + 512) * 16]);
    gl_lds16(gG0 + kb, &sBG[tid * 16]);
    gl_lds16(gG0 + kb + kstr, &sBG[(tid + 512) * 16]);
    gl_lds16(gU0 + kb, &sBU[tid * 16]);
    gl_lds16(gU0 + kb + kstr, &sBU[(tid + 512) * 16]);
    // scales: wave-uniform LDS base + lane*4 (m104); per-lane global source.
    if (wid == 0) gl_lds4(sAT + (long)g * M + m0 + lane, &sSa[0]);
    else if (wid == 1) gl_lds4(sAT + (long)g * M + m0 + 64 + lane, &sSa[64]);
    else if (wid == 2) gl_lds4(sGT + (long)g * N + n0 + lane, &sSg[0]);
    else if (wid == 3) gl_lds4(sGT + (long)g * N + n0 + 64 + lane, &sSg[64]);
    else if (wid == 4) gl_lds4(sUT + (long)g * N + n0 + lane, &sSu[0]);
    else if (wid == 5) gl_lds4(sUT + (long)g * N + n0 + 64 + lane, &sSu[64]);
    __syncthreads();

#pragma unroll
    for (int h = 0; h < 2; ++h) {  // i = h*2 + ii
      i32x4 af[2][2];
      f32x4 sa4[2];
#pragma unroll
      for (int ii = 0; ii < 2; ii++) {
        const int rb = (wr + (h * 2 + ii) * 16 + l15) * 128;
        af[ii][0] = *(const i32x4*)&sA[rb + colK0];
        af[ii][1] = *(const i32x4*)&sA[rb + colK1];
        sa4[ii] = *(const f32x4*)&sSa[wr + (h * 2 + ii) * 16 + l16 * 4];
      }
#pragma unroll
      for (int j = 0; j < 2; j++) {
        const int rbB = (wc + j * 16 + l15) * 128;
        i32x4 bgf[2], buf_[2];
        bgf[0] = *(const i32x4*)&sBG[rbB + colK0];
        bgf[1] = *(const i32x4*)&sBG[rbB + colK1];
        buf_[0] = *(const i32x4*)&sBU[rbB + colK0];
        buf_[1] = *(const i32x4*)&sBU[rbB + colK1];
        float sbg = sSg[wc + j * 16 + l15];
        float sbu = sSu[wc + j * 16 + l15];
#pragma unroll
        for (int ii = 0; ii < 2; ii++) {
          i32x4 tg = __builtin_amdgcn_mfma_i32_16x16x64_i8(af[ii][0], bgf[0], iz, 0, 0, 0);
          tg = __builtin_amdgcn_mfma_i32_16x16x64_i8(af[ii][1], bgf[1], tg, 0, 0, 0);
          i32x4 tu = __builtin_amdgcn_mfma_i32_16x16x64_i8(af[ii][0], buf_[0], iz, 0, 0, 0);
          tu = __builtin_amdgcn_mfma_i32_16x16x64_i8(af[ii][1], buf_[1], tu, 0, 0, 0);
          accg[h * 2 + ii][j] += (sa4[ii] * sbg) * __builtin_convertvector(tg, f32x4);
          accu[h * 2 + ii][j] += (sa4[ii] * sbu) * __builtin_convertvector(tu, f32x4);
        }
      }
    }
    __syncthreads();
  }

  // ---- epilogue: h = silu(g)*u; per-row (tile = one 128-col group) max -> s.
  float pm[4][4];
#pragma unroll
  for (int i = 0; i < 4; i++)
#pragma unroll
    for (int r = 0; r < 4; r++) pm[i][r] = 0.f;
#pragma unroll
  for (int i = 0; i < 4; i++)
#pragma unroll
    for (int j = 0; j < 2; j++)
#pragma unroll
      for (int r = 0; r < 4; r++) {
        float gv = accg[i][j][r];
        float h = gv / (1.f + expf(-gv)) * accu[i][j][r];
        accu[i][j][r] = h;
        pm[i][r] = fmaxf(pm[i][r], fabsf(h));
      }
#pragma unroll
  for (int i = 0; i < 4; i++)
#pragma unroll
    for (int r = 0; r < 4; r++) {
      pm[i][r] = fmaxf(pm[i][r], __shfl_xor(pm[i][r], 1));
      pm[i][r] = fmaxf(pm[i][r], __shfl_xor(pm[i][r], 2));
      pm[i][r] = fmaxf(pm[i][r], __shfl_xor(pm[i][r], 4));
      pm[i][r] = fmaxf(pm[i][r], __shfl_xor(pm[i][r], 8));
    }
#pragma unroll
  for (int i = 0; i < 4; i++)
#pragma unroll
    for (int r = 0; r < 4; r++)
      if (l15 == i * 4 + r) rmx[wn][wr + i * 16 + l16 * 4 + r] = pm[i][r];
  __syncthreads();
  if (tid < 128) {
    float mx = fmaxf(fmaxf(rmx[0][tid], rmx[1][tid]),
                     fmaxf(rmx[2][tid], rmx[3][tid]));
    float s = fmaxf(mx / QMAXF, EPSQ);
    rs[tid] = s;
    sHT[(n0 >> 7) * (long)M + m0 + tid] = s;
  }
  __syncthreads();
  // quantize into sA (K-loop done), then coalesced copy out
#pragma unroll
  for (int i = 0; i < 4; i++) {
    f32x4 sr = *(const f32x4*)&rs[wr + i * 16 + l16 * 4];
#pragma unroll
    for (int j = 0; j < 2; j++)
#pragma unroll
      for (int r = 0; r < 4; r++) {
        float qv = fminf(fmaxf(rintf(accu[i][j][r] / sr[r]), -QMAXF), QMAXF);
        sA[(wr + i * 16 + l16 * 4 + r) * 128 + wc + j * 16 + l15] = (char)(int)qv;
      }
  }
  __syncthreads();
  {
    long row = tid >> 2;
    int seg = (tid & 3) * 32;
    const i32x4* src = (const i32x4*)&sA[row * 128 + seg];
    i32x4* dst = (i32x4*)(Hq + (m0 + row) * N + n0 + seg);
    dst[0] = src[0];
    dst[1] = src[1];
  }
}

// Down GEMM: fp32 out = dequant(A_i8) . dequant(B_i8)^T with exact int cores.
// 128x256 tile, 8 waves (2wm x 4wn), per-wave 64x64.
__global__ __launch_bounds__(512, 4)
void gemm_dn_i8(const char* __restrict__ Aq, const char* __restrict__ Bq,
                const float* __restrict__ sAT, const float* __restrict__ sBT,
                float* __restrict__ C, int M, int N, int K, int NBN) {
  __shared__ __align__(16) char sA[16384];   // 128 rows
  __shared__ __align__(16) char sB[32768];   // 256 rows
  __shared__ float sSa[128], sSb[256];

  const int tid = threadIdx.x;
  const int lane = tid & 63;
  const int wid = tid >> 6;
  const int wm = wid >> 2, wn = wid & 3;
  const int wr = wm * 64, wc = wn * 64;
  const int l15 = lane & 15, l16 = lane >> 4;

  const int nwg = gridDim.x;
  const int wg = ((int)blockIdx.x & 7) * (nwg >> 3) + ((int)blockIdx.x >> 3);
  const long m0 = (long)(wg / NBN) * 128;
  const long n0 = (long)(wg % NBN) * 256;

  const long rowS = tid >> 3;
  const int offS = ((tid & 7) * 16) ^ ((int)(rowS & 7) << 4);
  const long kstr = 64L * K;
  const char* gA0 = Aq + (m0 + rowS) * K + offS;
  const char* gB0 = Bq + (n0 + rowS) * K + offS;

  const int rdSwz = (l15 & 7) << 4;
  const int colK0 = (l16 * 16) ^ rdSwz;
  const int colK1 = (64 + l16 * 16) ^ rdSwz;

  f32x4 acc[4][4];
#pragma unroll
  for (int i = 0; i < 4; i++)
#pragma unroll
    for (int j = 0; j < 4; j++) acc[i][j] = (f32x4){0.f, 0.f, 0.f, 0.f};
  const i32x4 iz = {0, 0, 0, 0};
  const int KG = K >> 7;

  for (int g = 0; g < KG; ++g) {
    const long kb = (long)g << 7;
    gl_lds16(gA0 + kb, &sA[tid * 16]);
    gl_lds16(gA0 + kb + kstr, &sA[(tid + 512) * 16]);
#pragma unroll
    for (int k = 0; k < 4; k++)
      gl_lds16(gB0 + kb + k * kstr, &sB[(tid + 512 * k) * 16]);
    if (wid == 0) gl_lds4(sAT + (long)g * M + m0 + lane, &sSa[0]);
    else if (wid == 1) gl_lds4(sAT + (long)g * M + m0 + 64 + lane, &sSa[64]);
    else if (wid >= 2 && wid <= 5)
      gl_lds4(sBT + (long)g * N + n0 + (wid - 2) * 64 + lane, &sSb[(wid - 2) * 64]);
    __syncthreads();

#pragma unroll
    for (int h = 0; h < 2; ++h) {  // i = h*2 + ii
      i32x4 af[2][2];
      f32x4 sa4[2];
#pragma unroll
      for (int ii = 0; ii < 2; ii++) {
        const int rb = (wr + (h * 2 + ii) * 16 + l15) * 128;
        af[ii][0] = *(const i32x4*)&sA[rb + colK0];
        af[ii][1] = *(const i32x4*)&sA[rb + colK1];
        sa4[ii] = *(const f32x4*)&sSa[wr + (h * 2 + ii) * 16 + l16 * 4];
      }
#pragma unroll
      for (int j = 0; j < 4; j++) {
        const int rbB = (wc + j * 16 + l15) * 128;
        i32x4 bf[2];
        bf[0] = *(const i32x4*)&sB[rbB + colK0];
        bf[1] = *(const i32x4*)&sB[rbB + colK1];
        float sb = sSb[wc + j * 16 + l15];
#pragma unroll
        for (int ii = 0; ii < 2; ii++) {
          i32x4 t = __builtin_amdgcn_mfma_i32_16x16x64_i8(af[ii][0], bf[0], iz, 0, 0, 0);
          t = __builtin_amdgcn_mfma_i32_16x16x64_i8(af[ii][1], bf[1], t, 0, 0, 0);
          acc[h * 2 + ii][j] += (sa4[ii] * sb) * __builtin_convertvector(t, f32x4);
        }
      }
    }
    __syncthreads();
  }

#pragma unroll
  for (int i = 0; i < 4; i++)
#pragma unroll
    for (int j = 0; j < 4; j++)
#pragma unroll
      for (int r = 0; r < 4; r++) {
        long row = m0 + wr + i * 16 + l16 * 4 + r;
        long col = n0 + wc + j * 16 + l15;
        C[row * N + col] = acc[i][j][r];
      }
}

extern "C" void kernel_launch(void* const* d_in, const int* in_sizes, int n_in,
                              void* d_out, int out_size, void* d_ws, size_t ws_size,
                              hipStream_t stream) {
  (void)n_in; (void)out_size;
  const float* x  = (const float*)d_in[0];
  const float* wg = (const float*)d_in[1];
  const float* wu = (const float*)d_in[2];
  const float* wd = (const float*)d_in[3];
  float* out = (float*)d_out;

  const long H = 4096;
  const long M = in_sizes[0] / H;   // 4096 (B*S)
  const long I = in_sizes[1] / H;   // 11008
  const long GH = H >> 7;           // 32
  const long GI = I >> 7;           // 86

  char* ws = (char*)d_ws;
  size_t off = 0;
  char* xq  = ws + off; off += (size_t)(M * H);
  char* wgq = ws + off; off += (size_t)(I * H);
  char* wuq = ws + off; off += (size_t)(I * H);
  char* wdq = ws + off; off += (size_t)(H * I);
  char* hq  = ws + off; off += (size_t)(M * I);
  float* s_x = (float*)(ws + off); off += (size_t)(GH * M) * 4;
  float* s_g = (float*)(ws + off); off += (size_t)(GH * I) * 4;
  float* s_u = (float*)(ws + off); off += (size_t)(GH * I) * 4;
  float* s_d = (float*)(ws + off); off += (size_t)(GI * H) * 4;
  float* s_h = (float*)(ws + off); off += (size_t)(GI * M) * 4;
  if (ws_size < off) return;

  // 1) int8 group-quant of inputs/weights (q + transposed scales)
  {
    long ng;
    ng = M * H / 128;
    qdq8<<<dim3((unsigned)((ng + 3) / 4)), dim3(256), 0, stream>>>(x, xq, s_x, ng, (int)GH, (int)M);
    ng = I * H / 128;
    qdq8<<<dim3((unsigned)((ng + 3) / 4)), dim3(256), 0, stream>>>(wg, wgq, s_g, ng, (int)GH, (int)I);
    qdq8<<<dim3((unsigned)((ng + 3) / 4)), dim3(256), 0, stream>>>(wu, wuq, s_u, ng, (int)GH, (int)I);
    ng = H * I / 128;
    qdq8<<<dim3((unsigned)((ng + 3) / 4)), dim3(256), 0, stream>>>(wd, wdq, s_d, ng, (int)GI, (int)H);
  }

  // 2) fused gate/up int8 GEMM + SwiGLU + hidden quant -> hq, s_h
  {
    const int NBN = (int)GI;                       // 86
    const int grid = (int)(M / 128) * NBN;         // 2752 (%8==0)
    gemm_gu_i8<<<dim3(grid), dim3(512), 0, stream>>>(
        xq, wgq, wuq, s_x, s_g, s_u, hq, s_h, (int)M, (int)I, (int)H, NBN);
  }
  // 3) down int8 GEMM -> fp32 out
  {
    const int NBN = (int)(H / 256);                // 16
    const int grid = (int)(M / 128) * NBN;         // 512 (%8==0)
    gemm_dn_i8<<<dim3(grid), dim3(512), 0, stream>>>(
        hq, wdq, s_h, s_d, out, (int)M, (int)H, (int)I, NBN);
  }
}

// Round 11
// 1989.938 us; speedup vs baseline: 1.5918x; 1.5918x over previous
//
#include <hip/hip_runtime.h>
#include <math.h>

typedef int i32x4 __attribute__((ext_vector_type(4)));
typedef float f32x4 __attribute__((ext_vector_type(4)));
typedef float f32x2 __attribute__((ext_vector_type(2)));

#define QMAXF 127.0f
#define EPSQ 1e-8f

__device__ __forceinline__ void gl_lds16(const void* g, void* l) {
  __builtin_amdgcn_global_load_lds(
      (const __attribute__((address_space(1))) unsigned int*)g,
      (__attribute__((address_space(3))) unsigned int*)l, 16, 0, 0);
}
__device__ __forceinline__ void gl_lds4(const void* g, void* l) {
  __builtin_amdgcn_global_load_lds(
      (const __attribute__((address_space(1))) unsigned int*)g,
      (__attribute__((address_space(3))) unsigned int*)l, 4, 0, 0);
}

// Group-of-128 symmetric int8 quant: fp32 in -> int8 q + transposed scales.
// Exact reference math in fp32 (max/127, maximum(.,eps), divide, rint, clip).
__global__ __launch_bounds__(256)
void qdq8(const float* __restrict__ in, char* __restrict__ q,
          float* __restrict__ sT, long n_groups, int gpr, int R) {
  long wid = (long)blockIdx.x * 4 + (threadIdx.x >> 6);
  if (wid >= n_groups) return;
  int lane = threadIdx.x & 63;
  long base = wid * 128 + lane * 2;
  f32x2 v = *(const f32x2*)(in + base);
  float m = fmaxf(fabsf(v.x), fabsf(v.y));
#pragma unroll
  for (int off = 32; off; off >>= 1) m = fmaxf(m, __shfl_xor(m, off));
  float s = fmaxf(m / QMAXF, EPSQ);
  int q0 = (int)fminf(fmaxf(rintf(v.x / s), -QMAXF), QMAXF);
  int q1 = (int)fminf(fmaxf(rintf(v.y / s), -QMAXF), QMAXF);
  *(unsigned short*)(q + base) =
      (unsigned short)((q0 & 0xff) | ((q1 & 0xff) << 8));
  if (lane == 0) {
    long row = wid / gpr;
    long gc = wid - row * gpr;
    sT[gc * (long)R + row] = s;
  }
}

// ---------------------------------------------------------------------------
// r8 skeleton (best measured: 256x128 tile, BK=128, 512 thr / 8 waves,
// LDS double-buffer, G4 XOR swizzle both sides, exact int32 MFMA + fp32
// rescale) with SOFTWARE-PIPELINED inner loop: per j-column, all 16 MFMAs
// are batched into temps t[j&1][..] and the rescale of column j-1 runs
// concurrently -- each wave keeps MFMA and VALU pipes simultaneously busy
// instead of alternating in dependent MFMA->cvt->fma bursts.
// ---------------------------------------------------------------------------

// gu LDS map (bytes): buf b at b*65536: A@0 (32K), BG@32768 (16K), BU@49152.
// scales @131072 + b*2048: sSa(1024) sSg@+1024(512) sSu@+1536(512).
// rmx@135168 (2048), rs@137216 (1024). Total 138240.
#define GU_SC 131072
#define GU_RMX 135168
#define GU_RS 137216
#define GU_LDS 138240

// Fused gate/up GEMM + SwiGLU + hidden group-quant (group = tile's 128 cols).
__global__ __launch_bounds__(512, 2)
void gemm_gu_i8(const char* __restrict__ Aq, const char* __restrict__ Bg,
                const char* __restrict__ Bu,
                const float* __restrict__ sAT, const float* __restrict__ sGT,
                const float* __restrict__ sUT,
                char* __restrict__ Hq, float* __restrict__ sHT,
                int M, int N, int K, int NBN) {
  extern __shared__ __align__(16) char smem[];
  const int tid = threadIdx.x;
  const int lane = tid & 63;
  const int wid = tid >> 6;
  const int wm = wid >> 1, wn = wid & 1;
  const int wr = wm * 64, wc = wn * 64;
  const int l15 = lane & 15, l16 = lane >> 4;

  const int nwg = gridDim.x;
  const int wg = ((int)blockIdx.x & 7) * (nwg >> 3) + ((int)blockIdx.x >> 3);
  const long m0 = (long)(wg / NBN) * 256;
  const long n0 = (long)(wg % NBN) * 128;

  // staging: chunk c = tid + 512k -> row = (tid>>3) + 64k, swizzled col.
  const long rowS = tid >> 3;
  const int offS = ((tid & 7) * 16) ^ ((int)(rowS & 7) << 4);
  const long kstr = 64L * K;
  const char* gA0 = Aq + (m0 + rowS) * K + offS;   // k = 0..3
  const char* gG0 = Bg + (n0 + rowS) * K + offS;   // k = 0..1
  const char* gU0 = Bu + (n0 + rowS) * K + offS;

  const int rdSwz = (l15 & 7) << 4;
  const int colK0 = (l16 * 16) ^ rdSwz;
  const int colK1 = (64 + l16 * 16) ^ rdSwz;

  f32x4 accg[4][4], accu[4][4];
#pragma unroll
  for (int i = 0; i < 4; i++)
#pragma unroll
    for (int j = 0; j < 4; j++) {
      accg[i][j] = (f32x4){0.f, 0.f, 0.f, 0.f};
      accu[i][j] = (f32x4){0.f, 0.f, 0.f, 0.f};
    }
  const i32x4 iz = {0, 0, 0, 0};
  const int KG = K >> 7;

#define GU_STAGE(gg, bb)                                                      \
  {                                                                           \
    const long kb = (long)(gg) << 7;                                          \
    char* tb = smem + (bb) * 65536;                                           \
    _Pragma("unroll") for (int k = 0; k < 4; k++)                             \
        gl_lds16(gA0 + kb + k * kstr, tb + (tid + 512 * k) * 16);             \
    _Pragma("unroll") for (int k = 0; k < 2; k++) {                           \
      gl_lds16(gG0 + kb + k * kstr, tb + 32768 + (tid + 512 * k) * 16);       \
      gl_lds16(gU0 + kb + k * kstr, tb + 49152 + (tid + 512 * k) * 16);       \
    }                                                                         \
    char* sc = smem + GU_SC + (bb) * 2048;                                    \
    if (wid < 4) {                                                            \
      gl_lds4(sAT + (long)(gg) * M + m0 + tid, sc + wid * 256);               \
    } else if (wid < 6) {                                                     \
      gl_lds4(sGT + (long)(gg) * N + n0 + (tid - 256), sc + 1024 + (wid - 4) * 256); \
    } else {                                                                  \
      gl_lds4(sUT + (long)(gg) * N + n0 + (tid - 384), sc + 1536 + (wid - 6) * 256); \
    }                                                                         \
  }

  GU_STAGE(0, 0);
  __syncthreads();

  for (int g = 0; g < KG; ++g) {
    const int cb = g & 1;
    if (g + 1 < KG) GU_STAGE(g + 1, cb ^ 1);

    const char* tb = smem + cb * 65536;
    const float* sc = (const float*)(smem + GU_SC + cb * 2048);

    i32x4 af[4][2];
#pragma unroll
    for (int i = 0; i < 4; i++) {
      const int rb = (wr + i * 16 + l15) * 128;
      af[i][0] = *(const i32x4*)(tb + rb + colK0);
      af[i][1] = *(const i32x4*)(tb + rb + colK1);
    }
    f32x4 sa4[4];
#pragma unroll
    for (int i = 0; i < 4; i++)
      sa4[i] = *(const f32x4*)(sc + wr + i * 16 + l16 * 4);

    // software-pipelined j loop: MFMA batch (j) overlaps rescale (j-1)
    i32x4 tg[2][4], tu[2][4];
    float sbgp[2], sbup[2];
#pragma unroll
    for (int j = 0; j < 4; j++) {
      const int cp = j & 1;
      const int rbB = (wc + j * 16 + l15) * 128;
      i32x4 bgf0 = *(const i32x4*)(tb + 32768 + rbB + colK0);
      i32x4 bgf1 = *(const i32x4*)(tb + 32768 + rbB + colK1);
      i32x4 buf0 = *(const i32x4*)(tb + 49152 + rbB + colK0);
      i32x4 buf1 = *(const i32x4*)(tb + 49152 + rbB + colK1);
      sbgp[cp] = sc[256 + wc + j * 16 + l15];
      sbup[cp] = sc[384 + wc + j * 16 + l15];
#pragma unroll
      for (int i = 0; i < 4; i++) {
        tg[cp][i] = __builtin_amdgcn_mfma_i32_16x16x64_i8(af[i][0], bgf0, iz, 0, 0, 0);
        tg[cp][i] = __builtin_amdgcn_mfma_i32_16x16x64_i8(af[i][1], bgf1, tg[cp][i], 0, 0, 0);
        tu[cp][i] = __builtin_amdgcn_mfma_i32_16x16x64_i8(af[i][0], buf0, iz, 0, 0, 0);
        tu[cp][i] = __builtin_amdgcn_mfma_i32_16x16x64_i8(af[i][1], buf1, tu[cp][i], 0, 0, 0);
      }
      if (j > 0) {
#pragma unroll
        for (int i = 0; i < 4; i++) {
          accg[i][j - 1] += (sa4[i] * sbgp[cp ^ 1]) * __builtin_convertvector(tg[cp ^ 1][i], f32x4);
          accu[i][j - 1] += (sa4[i] * sbup[cp ^ 1]) * __builtin_convertvector(tu[cp ^ 1][i], f32x4);
        }
      }
    }
#pragma unroll
    for (int i = 0; i < 4; i++) {
      accg[i][3] += (sa4[i] * sbgp[1]) * __builtin_convertvector(tg[1][i], f32x4);
      accu[i][3] += (sa4[i] * sbup[1]) * __builtin_convertvector(tu[1][i], f32x4);
    }
    __syncthreads();  // drains vmcnt: stage(g+1) resident; all reads of cb done
  }

  // ---- epilogue: h = silu(g)*u; per-row (128-col group) max -> s; quantize.
  float* rmx = (float*)(smem + GU_RMX);  // [2][256]
  float* rs = (float*)(smem + GU_RS);    // [256]
  float pm[4][4];
#pragma unroll
  for (int i = 0; i < 4; i++)
#pragma unroll
    for (int r = 0; r < 4; r++) pm[i][r] = 0.f;
#pragma unroll
  for (int i = 0; i < 4; i++)
#pragma unroll
    for (int j = 0; j < 4; j++)
#pragma unroll
      for (int r = 0; r < 4; r++) {
        float gv = accg[i][j][r];
        float h = gv / (1.f + expf(-gv)) * accu[i][j][r];
        accu[i][j][r] = h;
        pm[i][r] = fmaxf(pm[i][r], fabsf(h));
      }
#pragma unroll
  for (int i = 0; i < 4; i++)
#pragma unroll
    for (int r = 0; r < 4; r++) {
      pm[i][r] = fmaxf(pm[i][r], __shfl_xor(pm[i][r], 1));
      pm[i][r] = fmaxf(pm[i][r], __shfl_xor(pm[i][r], 2));
      pm[i][r] = fmaxf(pm[i][r], __shfl_xor(pm[i][r], 4));
      pm[i][r] = fmaxf(pm[i][r], __shfl_xor(pm[i][r], 8));
    }
#pragma unroll
  for (int i = 0; i < 4; i++)
#pragma unroll
    for (int r = 0; r < 4; r++)
      if (l15 == i * 4 + r) rmx[wn * 256 + wr + i * 16 + l16 * 4 + r] = pm[i][r];
  __syncthreads();
  if (tid < 256) {
    float mx = fmaxf(rmx[tid], rmx[256 + tid]);
    float s = fmaxf(mx / QMAXF, EPSQ);
    rs[tid] = s;
    sHT[(n0 >> 7) * (long)M + m0 + tid] = s;
  }
  __syncthreads();
  // quantize into buf0-A region (K-loop done), then coalesced copy out
  char* sQ = smem;  // 256 rows x 128 B
#pragma unroll
  for (int i = 0; i < 4; i++) {
    f32x4 sr = *(const f32x4*)(rs + wr + i * 16 + l16 * 4);
#pragma unroll
    for (int j = 0; j < 4; j++)
#pragma unroll
      for (int r = 0; r < 4; r++) {
        float qv = fminf(fmaxf(rintf(accu[i][j][r] / sr[r]), -QMAXF), QMAXF);
        sQ[(wr + i * 16 + l16 * 4 + r) * 128 + wc + j * 16 + l15] = (char)(int)qv;
      }
  }
  __syncthreads();
  {
    int row = tid >> 1, seg = tid & 1;
    const i32x4* src = (const i32x4*)(sQ + row * 128 + seg * 64);
    i32x4* dst = (i32x4*)(Hq + (m0 + row) * N + n0 + seg * 64);
#pragma unroll
    for (int k = 0; k < 4; k++) dst[k] = src[k];
  }
}

// dn LDS map: buf b at b*49152: A@0 (32K), B@32768 (16K).
// scales @98304 + b*1536: sSa(1024) sSb@+1024(512). Total 101376.
#define DN_SC 98304
#define DN_LDS 101376

// Down GEMM: fp32 out = dequant(A_i8) . dequant(B_i8)^T with exact int cores.
__global__ __launch_bounds__(512, 2)
void gemm_dn_i8(const char* __restrict__ Aq, const char* __restrict__ Bq,
                const float* __restrict__ sAT, const float* __restrict__ sBT,
                float* __restrict__ C, int M, int N, int K, int NBN) {
  extern __shared__ __align__(16) char smem[];
  const int tid = threadIdx.x;
  const int lane = tid & 63;
  const int wid = tid >> 6;
  const int wm = wid >> 1, wn = wid & 1;
  const int wr = wm * 64, wc = wn * 64;
  const int l15 = lane & 15, l16 = lane >> 4;

  const int nwg = gridDim.x;
  const int wg = ((int)blockIdx.x & 7) * (nwg >> 3) + ((int)blockIdx.x >> 3);
  const long m0 = (long)(wg / NBN) * 256;
  const long n0 = (long)(wg % NBN) * 128;

  const long rowS = tid >> 3;
  const int offS = ((tid & 7) * 16) ^ ((int)(rowS & 7) << 4);
  const long kstr = 64L * K;
  const char* gA0 = Aq + (m0 + rowS) * K + offS;
  const char* gB0 = Bq + (n0 + rowS) * K + offS;

  const int rdSwz = (l15 & 7) << 4;
  const int colK0 = (l16 * 16) ^ rdSwz;
  const int colK1 = (64 + l16 * 16) ^ rdSwz;

  f32x4 acc[4][4];
#pragma unroll
  for (int i = 0; i < 4; i++)
#pragma unroll
    for (int j = 0; j < 4; j++) acc[i][j] = (f32x4){0.f, 0.f, 0.f, 0.f};
  const i32x4 iz = {0, 0, 0, 0};
  const int KG = K >> 7;

#define DN_STAGE(gg, bb)                                                      \
  {                                                                           \
    const long kb = (long)(gg) << 7;                                          \
    char* tb = smem + (bb) * 49152;                                           \
    _Pragma("unroll") for (int k = 0; k < 4; k++)                             \
        gl_lds16(gA0 + kb + k * kstr, tb + (tid + 512 * k) * 16);             \
    _Pragma("unroll") for (int k = 0; k < 2; k++)                             \
        gl_lds16(gB0 + kb + k * kstr, tb + 32768 + (tid + 512 * k) * 16);     \
    char* sc = smem + DN_SC + (bb) * 1536;                                    \
    if (wid < 4) {                                                            \
      gl_lds4(sAT + (long)(gg) * M + m0 + tid, sc + wid * 256);               \
    } else if (wid < 6) {                                                     \
      gl_lds4(sBT + (long)(gg) * N + n0 + (tid - 256), sc + 1024 + (wid - 4) * 256); \
    }                                                                         \
  }

  DN_STAGE(0, 0);
  __syncthreads();

  for (int g = 0; g < KG; ++g) {
    const int cb = g & 1;
    if (g + 1 < KG) DN_STAGE(g + 1, cb ^ 1);

    const char* tb = smem + cb * 49152;
    const float* sc = (const float*)(smem + DN_SC + cb * 1536);

    i32x4 af[4][2];
#pragma unroll
    for (int i = 0; i < 4; i++) {
      const int rb = (wr + i * 16 + l15) * 128;
      af[i][0] = *(const i32x4*)(tb + rb + colK0);
      af[i][1] = *(const i32x4*)(tb + rb + colK1);
    }
    f32x4 sa4[4];
#pragma unroll
    for (int i = 0; i < 4; i++)
      sa4[i] = *(const f32x4*)(sc + wr + i * 16 + l16 * 4);

    i32x4 t[2][4];
    float sbp[2];
#pragma unroll
    for (int j = 0; j < 4; j++) {
      const int cp = j & 1;
      const int rbB = (wc + j * 16 + l15) * 128;
      i32x4 bf0 = *(const i32x4*)(tb + 32768 + rbB + colK0);
      i32x4 bf1 = *(const i32x4*)(tb + 32768 + rbB + colK1);
      sbp[cp] = sc[256 + wc + j * 16 + l15];
#pragma unroll
      for (int i = 0; i < 4; i++) {
        t[cp][i] = __builtin_amdgcn_mfma_i32_16x16x64_i8(af[i][0], bf0, iz, 0, 0, 0);
        t[cp][i] = __builtin_amdgcn_mfma_i32_16x16x64_i8(af[i][1], bf1, t[cp][i], 0, 0, 0);
      }
      if (j > 0) {
#pragma unroll
        for (int i = 0; i < 4; i++)
          acc[i][j - 1] += (sa4[i] * sbp[cp ^ 1]) * __builtin_convertvector(t[cp ^ 1][i], f32x4);
      }
    }
#pragma unroll
    for (int i = 0; i < 4; i++)
      acc[i][3] += (sa4[i] * sbp[1]) * __builtin_convertvector(t[1][i], f32x4);
    __syncthreads();
  }

#pragma unroll
  for (int i = 0; i < 4; i++)
#pragma unroll
    for (int j = 0; j < 4; j++)
#pragma unroll
      for (int r = 0; r < 4; r++) {
        long row = m0 + wr + i * 16 + l16 * 4 + r;
        long col = n0 + wc + j * 16 + l15;
        C[row * N + col] = acc[i][j][r];
      }
}

extern "C" void kernel_launch(void* const* d_in, const int* in_sizes, int n_in,
                              void* d_out, int out_size, void* d_ws, size_t ws_size,
                              hipStream_t stream) {
  (void)n_in; (void)out_size;
  const float* x  = (const float*)d_in[0];
  const float* wg = (const float*)d_in[1];
  const float* wu = (const float*)d_in[2];
  const float* wd = (const float*)d_in[3];
  float* out = (float*)d_out;

  const long H = 4096;
  const long M = in_sizes[0] / H;   // 4096 (B*S)
  const long I = in_sizes[1] / H;   // 11008
  const long GH = H >> 7;           // 32
  const long GI = I >> 7;           // 86

  char* ws = (char*)d_ws;
  size_t off = 0;
  char* xq  = ws + off; off += (size_t)(M * H);
  char* wgq = ws + off; off += (size_t)(I * H);
  char* wuq = ws + off; off += (size_t)(I * H);
  char* wdq = ws + off; off += (size_t)(H * I);
  char* hq  = ws + off; off += (size_t)(M * I);
  float* s_x = (float*)(ws + off); off += (size_t)(GH * M) * 4;
  float* s_g = (float*)(ws + off); off += (size_t)(GH * I) * 4;
  float* s_u = (float*)(ws + off); off += (size_t)(GH * I) * 4;
  float* s_d = (float*)(ws + off); off += (size_t)(GI * H) * 4;
  float* s_h = (float*)(ws + off); off += (size_t)(GI * M) * 4;
  if (ws_size < off) return;

  hipFuncSetAttribute((const void*)gemm_gu_i8,
                      hipFuncAttributeMaxDynamicSharedMemorySize, GU_LDS);
  hipFuncSetAttribute((const void*)gemm_dn_i8,
                      hipFuncAttributeMaxDynamicSharedMemorySize, DN_LDS);

  // 1) int8 group-quant of inputs/weights (q + transposed scales)
  {
    long ng;
    ng = M * H / 128;
    qdq8<<<dim3((unsigned)((ng + 3) / 4)), dim3(256), 0, stream>>>(x, xq, s_x, ng, (int)GH, (int)M);
    ng = I * H / 128;
    qdq8<<<dim3((unsigned)((ng + 3) / 4)), dim3(256), 0, stream>>>(wg, wgq, s_g, ng, (int)GH, (int)I);
    qdq8<<<dim3((unsigned)((ng + 3) / 4)), dim3(256), 0, stream>>>(wu, wuq, s_u, ng, (int)GH, (int)I);
    ng = H * I / 128;
    qdq8<<<dim3((unsigned)((ng + 3) / 4)), dim3(256), 0, stream>>>(wd, wdq, s_d, ng, (int)GI, (int)H);
  }

  // 2) fused gate/up int8 GEMM + SwiGLU + hidden quant -> hq, s_h
  {
    const int NBN = (int)GI;                       // 86
    const int grid = (int)(M / 256) * NBN;         // 1376 (%8==0)
    gemm_gu_i8<<<dim3(grid), dim3(512), GU_LDS, stream>>>(
        xq, wgq, wuq, s_x, s_g, s_u, hq, s_h, (int)M, (int)I, (int)H, NBN);
  }
  // 3) down int8 GEMM -> fp32 out
  {
    const int NBN = (int)GH;                       // 32
    const int grid = (int)(M / 256) * NBN;         // 512 (%8==0)
    gemm_dn_i8<<<dim3(grid), dim3(512), DN_LDS, stream>>>(
        hq, wdq, s_h, s_d, out, (int)M, (int)H, (int)I, NBN);
  }
}

// Round 12
// 1134.728 us; speedup vs baseline: 2.7915x; 1.7537x over previous
//
#include <hip/hip_runtime.h>
#include <math.h>

typedef int i32x4 __attribute__((ext_vector_type(4)));
typedef float f32x4 __attribute__((ext_vector_type(4)));
typedef float f32x2 __attribute__((ext_vector_type(2)));

#define QMAXF 127.0f
#define EPSQ 1e-8f

__device__ __forceinline__ void gl_lds16(const void* g, void* l) {
  __builtin_amdgcn_global_load_lds(
      (const __attribute__((address_space(1))) unsigned int*)g,
      (__attribute__((address_space(3))) unsigned int*)l, 16, 0, 0);
}
__device__ __forceinline__ void gl_lds4(const void* g, void* l) {
  __builtin_amdgcn_global_load_lds(
      (const __attribute__((address_space(1))) unsigned int*)g,
      (__attribute__((address_space(3))) unsigned int*)l, 4, 0, 0);
}

// Group-of-128 symmetric int8 quant: fp32 in -> int8 q + transposed scales.
// Exact reference math in fp32 (max/127, maximum(.,eps), divide, rint, clip).
__global__ __launch_bounds__(256)
void qdq8(const float* __restrict__ in, char* __restrict__ q,
          float* __restrict__ sT, long n_groups, int gpr, int R) {
  long wid = (long)blockIdx.x * 4 + (threadIdx.x >> 6);
  if (wid >= n_groups) return;
  int lane = threadIdx.x & 63;
  long base = wid * 128 + lane * 2;
  f32x2 v = *(const f32x2*)(in + base);
  float m = fmaxf(fabsf(v.x), fabsf(v.y));
#pragma unroll
  for (int off = 32; off; off >>= 1) m = fmaxf(m, __shfl_xor(m, off));
  float s = fmaxf(m / QMAXF, EPSQ);
  int q0 = (int)fminf(fmaxf(rintf(v.x / s), -QMAXF), QMAXF);
  int q1 = (int)fminf(fmaxf(rintf(v.y / s), -QMAXF), QMAXF);
  *(unsigned short*)(q + base) =
      (unsigned short)((q0 & 0xff) | ((q1 & 0xff) << 8));
  if (lane == 0) {
    long row = wid / gpr;
    long gc = wid - row * gpr;
    sT[gc * (long)R + row] = s;
  }
}

// ---------------------------------------------------------------------------
// v12: occupancy via single-dtype waves at unchanged tile sizes.
// gu: 128x128 tile, 1024 thr / 16 waves; waves 0-7 gate, 8-15 up, each owns
//     a 64x32 sub-tile (acc = 32 f32 -> wave state ~100 regs). 4 waves/SIMD
//     at 1 block/CU ((1024,4) -> 128-reg budget). SwiGLU fused via 64KB LDS
//     gate-exchange overlaying the dead K-tile buffers after the K-loop.
// dn: 256x128 tile, 16 waves of 64x32 single dtype.
// Both keep r8's double-buffered staging (stage(g+1) issued before
// compute(g)), G4 XOR swizzle both sides, exact int32 MFMA + fp32 rescale.
// ---------------------------------------------------------------------------

// gu LDS (bytes): buf b at b*49152: A@0 (16K), BG@16384, BU@32768.
// scales @98304 + b*1536 (sSa 512B, sSg 512B, sSu 512B).
// rmx@101376 (2048 = 4x128 f32), rs@103424 (512). Total 103936.
// gexch (128x128 f32 = 64K) overlays smem[0..65536) after K-loop.
#define GU_SC 98304
#define GU_RMX 101376
#define GU_RS 103424
#define GU_LDS 103936

__global__ __launch_bounds__(1024, 4)
void gemm_gu_i8(const char* __restrict__ Aq, const char* __restrict__ Bg,
                const char* __restrict__ Bu,
                const float* __restrict__ sAT, const float* __restrict__ sGT,
                const float* __restrict__ sUT,
                char* __restrict__ Hq, float* __restrict__ sHT,
                int M, int N, int K, int NBN) {
  extern __shared__ __align__(16) char smem[];
  const int tid = threadIdx.x;
  const int lane = tid & 63;
  const int wid = tid >> 6;
  const int w8 = wid & 7;
  const bool is_up = wid >= 8;
  const int wr = (w8 >> 2) * 64;   // 0 or 64
  const int wc = (w8 & 3) * 32;    // 0,32,64,96
  const int l15 = lane & 15, l16 = lane >> 4;

  const int nwg = gridDim.x;
  const int wg = ((int)blockIdx.x & 7) * (nwg >> 3) + ((int)blockIdx.x >> 3);
  const long m0 = (long)(wg / NBN) * 128;
  const long n0 = (long)(wg % NBN) * 128;

  // staging: each 16KB region = 1024 chunks, 1 per thread.
  const long rowS = tid >> 3;  // 0..127
  const int offS = ((tid & 7) * 16) ^ ((int)(rowS & 7) << 4);
  const char* gA0 = Aq + (m0 + rowS) * K + offS;
  const char* gG0 = Bg + (n0 + rowS) * K + offS;
  const char* gU0 = Bu + (n0 + rowS) * K + offS;

  const int rdSwz = (l15 & 7) << 4;
  const int colK0 = (l16 * 16) ^ rdSwz;
  const int colK1 = (64 + l16 * 16) ^ rdSwz;

  f32x4 acc[4][2];
#pragma unroll
  for (int i = 0; i < 4; i++)
#pragma unroll
    for (int j = 0; j < 2; j++) acc[i][j] = (f32x4){0.f, 0.f, 0.f, 0.f};
  const i32x4 iz = {0, 0, 0, 0};
  const int KG = K >> 7;

#define GU_STAGE(gg, bb)                                                      \
  {                                                                           \
    const long kb = (long)(gg) << 7;                                          \
    char* tb = smem + (bb) * 49152;                                           \
    gl_lds16(gA0 + kb, tb + tid * 16);                                        \
    gl_lds16(gG0 + kb, tb + 16384 + tid * 16);                                \
    gl_lds16(gU0 + kb, tb + 32768 + tid * 16);                                \
    char* sc = smem + GU_SC + (bb) * 1536;                                    \
    if (wid == 0)      gl_lds4(sAT + (long)(gg) * M + m0 + lane,      sc);        \
    else if (wid == 1) gl_lds4(sAT + (long)(gg) * M + m0 + 64 + lane, sc + 256);  \
    else if (wid == 2) gl_lds4(sGT + (long)(gg) * N + n0 + lane,      sc + 512);  \
    else if (wid == 3) gl_lds4(sGT + (long)(gg) * N + n0 + 64 + lane, sc + 768);  \
    else if (wid == 4) gl_lds4(sUT + (long)(gg) * N + n0 + lane,      sc + 1024); \
    else if (wid == 5) gl_lds4(sUT + (long)(gg) * N + n0 + 64 + lane, sc + 1280); \
  }

  GU_STAGE(0, 0);
  __syncthreads();

  for (int g = 0; g < KG; ++g) {
    const int cb = g & 1;
    if (g + 1 < KG) GU_STAGE(g + 1, cb ^ 1);

    const char* tb = smem + cb * 49152;
    const char* tbB = tb + (is_up ? 32768 : 16384);
    const float* scp = (const float*)(smem + GU_SC + cb * 1536);

    i32x4 af[4][2];
#pragma unroll
    for (int i = 0; i < 4; i++) {
      const int rb = (wr + i * 16 + l15) * 128;
      af[i][0] = *(const i32x4*)(tb + rb + colK0);
      af[i][1] = *(const i32x4*)(tb + rb + colK1);
    }
    f32x4 sa4[4];
#pragma unroll
    for (int i = 0; i < 4; i++)
      sa4[i] = *(const f32x4*)(scp + wr + i * 16 + l16 * 4);
    const int sbBase = is_up ? 256 : 128;
#pragma unroll
    for (int j = 0; j < 2; j++) {
      const int rbB = (wc + j * 16 + l15) * 128;
      i32x4 bf0 = *(const i32x4*)(tbB + rbB + colK0);
      i32x4 bf1 = *(const i32x4*)(tbB + rbB + colK1);
      float sb = scp[sbBase + wc + j * 16 + l15];
#pragma unroll
      for (int i = 0; i < 4; i++) {
        i32x4 t = __builtin_amdgcn_mfma_i32_16x16x64_i8(af[i][0], bf0, iz, 0, 0, 0);
        t = __builtin_amdgcn_mfma_i32_16x16x64_i8(af[i][1], bf1, t, 0, 0, 0);
        acc[i][j] += (sa4[i] * sb) * __builtin_convertvector(t, f32x4);
      }
    }
    __syncthreads();  // drains vmcnt: stage(g+1) resident; all reads of cb done
  }

  // ---- epilogue: gate waves publish acc via LDS; up waves apply SwiGLU,
  // per-row (128-col group) max -> s, quantize, write hq + sHT.
  float* gexch = (float*)smem;  // [128][128] f32, overlays dead K-tile bufs
  if (!is_up) {
#pragma unroll
    for (int i = 0; i < 4; i++)
#pragma unroll
      for (int j = 0; j < 2; j++)
#pragma unroll
        for (int r = 0; r < 4; r++)
          gexch[(wr + i * 16 + l16 * 4 + r) * 128 + wc + j * 16 + l15] = acc[i][j][r];
  }
  __syncthreads();
  float* rmx = (float*)(smem + GU_RMX);  // [4][128]
  float* rs = (float*)(smem + GU_RS);    // [128]
  if (is_up) {
    float pm[4][4];
#pragma unroll
    for (int i = 0; i < 4; i++)
#pragma unroll
      for (int r = 0; r < 4; r++) pm[i][r] = 0.f;
#pragma unroll
    for (int i = 0; i < 4; i++)
#pragma unroll
      for (int j = 0; j < 2; j++)
#pragma unroll
        for (int r = 0; r < 4; r++) {
          int row = wr + i * 16 + l16 * 4 + r;
          int col = wc + j * 16 + l15;
          float gv = gexch[row * 128 + col];
          float h = gv / (1.f + expf(-gv)) * acc[i][j][r];
          acc[i][j][r] = h;
          pm[i][r] = fmaxf(pm[i][r], fabsf(h));
        }
#pragma unroll
    for (int i = 0; i < 4; i++)
#pragma unroll
      for (int r = 0; r < 4; r++) {
        pm[i][r] = fmaxf(pm[i][r], __shfl_xor(pm[i][r], 1));
        pm[i][r] = fmaxf(pm[i][r], __shfl_xor(pm[i][r], 2));
        pm[i][r] = fmaxf(pm[i][r], __shfl_xor(pm[i][r], 4));
        pm[i][r] = fmaxf(pm[i][r], __shfl_xor(pm[i][r], 8));
      }
#pragma unroll
    for (int i = 0; i < 4; i++)
#pragma unroll
      for (int r = 0; r < 4; r++)
        if (l15 == i * 4 + r)
          rmx[(w8 & 3) * 128 + wr + i * 16 + l16 * 4 + r] = pm[i][r];
  }
  __syncthreads();
  if (tid < 128) {
    float mx = fmaxf(fmaxf(rmx[tid], rmx[128 + tid]),
                     fmaxf(rmx[256 + tid], rmx[384 + tid]));
    float s = fmaxf(mx / QMAXF, EPSQ);
    rs[tid] = s;
    sHT[(n0 >> 7) * (long)M + m0 + tid] = s;
  }
  __syncthreads();
  char* qb = smem;  // 128x128 i8 @ [0,16384), gexch dead now
  if (is_up) {
#pragma unroll
    for (int i = 0; i < 4; i++) {
      f32x4 sr = *(const f32x4*)(rs + wr + i * 16 + l16 * 4);
#pragma unroll
      for (int j = 0; j < 2; j++)
#pragma unroll
        for (int r = 0; r < 4; r++) {
          float qv = fminf(fmaxf(rintf(acc[i][j][r] / sr[r]), -QMAXF), QMAXF);
          qb[(wr + i * 16 + l16 * 4 + r) * 128 + wc + j * 16 + l15] = (char)(int)qv;
        }
    }
  }
  __syncthreads();
  {
    long row = tid >> 3;
    int off = (tid & 7) * 16;
    *(i32x4*)(Hq + (m0 + row) * N + n0 + off) = *(const i32x4*)(qb + row * 128 + off);
  }
}

// dn LDS: buf b at b*49152: A@0 (32K, 256 rows), B@32768 (16K, 128 rows).
// scales @98304 + b*1536 (sSa 1024B, sSb 512B). Total 101376.
#define DN_SC 98304
#define DN_LDS 101376

// Down GEMM: fp32 out = dequant(A_i8) . dequant(B_i8)^T with exact int cores.
// 256x128 tile, 16 waves (4wm x 4wn) of 64x32.
__global__ __launch_bounds__(1024, 4)
void gemm_dn_i8(const char* __restrict__ Aq, const char* __restrict__ Bq,
                const float* __restrict__ sAT, const float* __restrict__ sBT,
                float* __restrict__ C, int M, int N, int K, int NBN) {
  extern __shared__ __align__(16) char smem[];
  const int tid = threadIdx.x;
  const int lane = tid & 63;
  const int wid = tid >> 6;
  const int wr = (wid >> 2) * 64;  // 0..192
  const int wc = (wid & 3) * 32;   // 0..96
  const int l15 = lane & 15, l16 = lane >> 4;

  const int nwg = gridDim.x;
  const int wg = ((int)blockIdx.x & 7) * (nwg >> 3) + ((int)blockIdx.x >> 3);
  const long m0 = (long)(wg / NBN) * 256;
  const long n0 = (long)(wg % NBN) * 128;

  const long rowS = tid >> 3;  // 0..127
  const int offS = ((tid & 7) * 16) ^ ((int)(rowS & 7) << 4);
  const char* gA0 = Aq + (m0 + rowS) * K + offS;       // rows rowS, rowS+128
  const char* gA1 = gA0 + 128L * K;
  const char* gB0 = Bq + (n0 + rowS) * K + offS;

  const int rdSwz = (l15 & 7) << 4;
  const int colK0 = (l16 * 16) ^ rdSwz;
  const int colK1 = (64 + l16 * 16) ^ rdSwz;

  f32x4 acc[4][2];
#pragma unroll
  for (int i = 0; i < 4; i++)
#pragma unroll
    for (int j = 0; j < 2; j++) acc[i][j] = (f32x4){0.f, 0.f, 0.f, 0.f};
  const i32x4 iz = {0, 0, 0, 0};
  const int KG = K >> 7;

#define DN_STAGE(gg, bb)                                                      \
  {                                                                           \
    const long kb = (long)(gg) << 7;                                          \
    char* tb = smem + (bb) * 49152;                                           \
    gl_lds16(gA0 + kb, tb + tid * 16);                                        \
    gl_lds16(gA1 + kb, tb + 16384 + tid * 16);                                \
    gl_lds16(gB0 + kb, tb + 32768 + tid * 16);                                \
    char* sc = smem + DN_SC + (bb) * 1536;                                    \
    if (wid == 0)      gl_lds4(sAT + (long)(gg) * M + m0 + lane,       sc);        \
    else if (wid == 1) gl_lds4(sAT + (long)(gg) * M + m0 + 64 + lane,  sc + 256);  \
    else if (wid == 2) gl_lds4(sAT + (long)(gg) * M + m0 + 128 + lane, sc + 512);  \
    else if (wid == 3) gl_lds4(sAT + (long)(gg) * M + m0 + 192 + lane, sc + 768);  \
    else if (wid == 4) gl_lds4(sBT + (long)(gg) * N + n0 + lane,       sc + 1024); \
    else if (wid == 5) gl_lds4(sBT + (long)(gg) * N + n0 + 64 + lane,  sc + 1280); \
  }

  DN_STAGE(0, 0);
  __syncthreads();

  for (int g = 0; g < KG; ++g) {
    const int cb = g & 1;
    if (g + 1 < KG) DN_STAGE(g + 1, cb ^ 1);

    const char* tb = smem + cb * 49152;
    const float* scp = (const float*)(smem + DN_SC + cb * 1536);

    i32x4 af[4][2];
#pragma unroll
    for (int i = 0; i < 4; i++) {
      const int rb = (wr + i * 16 + l15) * 128;
      af[i][0] = *(const i32x4*)(tb + rb + colK0);
      af[i][1] = *(const i32x4*)(tb + rb + colK1);
    }
    f32x4 sa4[4];
#pragma unroll
    for (int i = 0; i < 4; i++)
      sa4[i] = *(const f32x4*)(scp + wr + i * 16 + l16 * 4);
#pragma unroll
    for (int j = 0; j < 2; j++) {
      const int rbB = (wc + j * 16 + l15) * 128;
      i32x4 bf0 = *(const i32x4*)(tb + 32768 + rbB + colK0);
      i32x4 bf1 = *(const i32x4*)(tb + 32768 + rbB + colK1);
      float sb = scp[256 + wc + j * 16 + l15];
#pragma unroll
      for (int i = 0; i < 4; i++) {
        i32x4 t = __builtin_amdgcn_mfma_i32_16x16x64_i8(af[i][0], bf0, iz, 0, 0, 0);
        t = __builtin_amdgcn_mfma_i32_16x16x64_i8(af[i][1], bf1, t, 0, 0, 0);
        acc[i][j] += (sa4[i] * sb) * __builtin_convertvector(t, f32x4);
      }
    }
    __syncthreads();
  }

#pragma unroll
  for (int i = 0; i < 4; i++)
#pragma unroll
    for (int j = 0; j < 2; j++)
#pragma unroll
      for (int r = 0; r < 4; r++) {
        long row = m0 + wr + i * 16 + l16 * 4 + r;
        long col = n0 + wc + j * 16 + l15;
        C[row * N + col] = acc[i][j][r];
      }
}

extern "C" void kernel_launch(void* const* d_in, const int* in_sizes, int n_in,
                              void* d_out, int out_size, void* d_ws, size_t ws_size,
                              hipStream_t stream) {
  (void)n_in; (void)out_size;
  const float* x  = (const float*)d_in[0];
  const float* wg = (const float*)d_in[1];
  const float* wu = (const float*)d_in[2];
  const float* wd = (const float*)d_in[3];
  float* out = (float*)d_out;

  const long H = 4096;
  const long M = in_sizes[0] / H;   // 4096 (B*S)
  const long I = in_sizes[1] / H;   // 11008
  const long GH = H >> 7;           // 32
  const long GI = I >> 7;           // 86

  char* ws = (char*)d_ws;
  size_t off = 0;
  char* xq  = ws + off; off += (size_t)(M * H);
  char* wgq = ws + off; off += (size_t)(I * H);
  char* wuq = ws + off; off += (size_t)(I * H);
  char* wdq = ws + off; off += (size_t)(H * I);
  char* hq  = ws + off; off += (size_t)(M * I);
  float* s_x = (float*)(ws + off); off += (size_t)(GH * M) * 4;
  float* s_g = (float*)(ws + off); off += (size_t)(GH * I) * 4;
  float* s_u = (float*)(ws + off); off += (size_t)(GH * I) * 4;
  float* s_d = (float*)(ws + off); off += (size_t)(GI * H) * 4;
  float* s_h = (float*)(ws + off); off += (size_t)(GI * M) * 4;
  if (ws_size < off) return;

  hipFuncSetAttribute((const void*)gemm_gu_i8,
                      hipFuncAttributeMaxDynamicSharedMemorySize, GU_LDS);
  hipFuncSetAttribute((const void*)gemm_dn_i8,
                      hipFuncAttributeMaxDynamicSharedMemorySize, DN_LDS);

  // 1) int8 group-quant of inputs/weights (q + transposed scales)
  {
    long ng;
    ng = M * H / 128;
    qdq8<<<dim3((unsigned)((ng + 3) / 4)), dim3(256), 0, stream>>>(x, xq, s_x, ng, (int)GH, (int)M);
    ng = I * H / 128;
    qdq8<<<dim3((unsigned)((ng + 3) / 4)), dim3(256), 0, stream>>>(wg, wgq, s_g, ng, (int)GH, (int)I);
    qdq8<<<dim3((unsigned)((ng + 3) / 4)), dim3(256), 0, stream>>>(wu, wuq, s_u, ng, (int)GH, (int)I);
    ng = H * I / 128;
    qdq8<<<dim3((unsigned)((ng + 3) / 4)), dim3(256), 0, stream>>>(wd, wdq, s_d, ng, (int)GI, (int)H);
  }

  // 2) fused gate/up int8 GEMM + SwiGLU + hidden quant -> hq, s_h
  {
    const int NBN = (int)GI;                       // 86
    const int grid = (int)(M / 128) * NBN;         // 2752 (%8==0)
    gemm_gu_i8<<<dim3(grid), dim3(1024), GU_LDS, stream>>>(
        xq, wgq, wuq, s_x, s_g, s_u, hq, s_h, (int)M, (int)I, (int)H, NBN);
  }
  // 3) down int8 GEMM -> fp32 out
  {
    const int NBN = (int)GH;                       // 32
    const int grid = (int)(M / 256) * NBN;         // 512 (%8==0)
    gemm_dn_i8<<<dim3(grid), dim3(1024), DN_LDS, stream>>>(
        hq, wdq, s_h, s_d, out, (int)M, (int)H, (int)I, NBN);
  }
}

// Round 13
// 1070.255 us; speedup vs baseline: 2.9597x; 1.0602x over previous
//
#include <hip/hip_runtime.h>
#include <math.h>

typedef int i32x4 __attribute__((ext_vector_type(4)));
typedef float f32x4 __attribute__((ext_vector_type(4)));
typedef float f32x2 __attribute__((ext_vector_type(2)));

#define QMAXF 127.0f
#define EPSQ 1e-8f

__device__ __forceinline__ void gl_lds16(const void* g, void* l) {
  __builtin_amdgcn_global_load_lds(
      (const __attribute__((address_space(1))) unsigned int*)g,
      (__attribute__((address_space(3))) unsigned int*)l, 16, 0, 0);
}
__device__ __forceinline__ void gl_lds4(const void* g, void* l) {
  __builtin_amdgcn_global_load_lds(
      (const __attribute__((address_space(1))) unsigned int*)g,
      (__attribute__((address_space(3))) unsigned int*)l, 4, 0, 0);
}

// Group-of-128 symmetric int8 quant: fp32 in -> int8 q + transposed scales.
// Exact reference math in fp32 (max/127, maximum(.,eps), divide, rint, clip).
// v13: f32x4 loads (16B/lane, G13), one group per 32-lane half-wave,
// packed int32 store -- halves instruction count on a memory-bound kernel.
__global__ __launch_bounds__(256)
void qdq8(const float* __restrict__ in, char* __restrict__ q,
          float* __restrict__ sT, long n_groups, int gpr, int R) {
  long grp = (long)blockIdx.x * 8 + (threadIdx.x >> 5);
  if (grp >= n_groups) return;
  int hl = threadIdx.x & 31;
  long base = grp * 128 + hl * 4;
  f32x4 v = *(const f32x4*)(in + base);
  float m = fmaxf(fmaxf(fabsf(v.x), fabsf(v.y)), fmaxf(fabsf(v.z), fabsf(v.w)));
#pragma unroll
  for (int off = 16; off; off >>= 1) m = fmaxf(m, __shfl_xor(m, off));
  float s = fmaxf(m / QMAXF, EPSQ);
  int q0 = (int)fminf(fmaxf(rintf(v.x / s), -QMAXF), QMAXF);
  int q1 = (int)fminf(fmaxf(rintf(v.y / s), -QMAXF), QMAXF);
  int q2 = (int)fminf(fmaxf(rintf(v.z / s), -QMAXF), QMAXF);
  int q3 = (int)fminf(fmaxf(rintf(v.w / s), -QMAXF), QMAXF);
  *(int*)(q + base) = (q0 & 0xff) | ((q1 & 0xff) << 8) |
                      ((q2 & 0xff) << 16) | ((q3 & 0xff) << 24);
  if (hl == 0) {
    long row = grp / gpr;
    long gc = grp - row * gpr;
    sT[gc * (long)R + row] = s;
  }
}

// ---------------------------------------------------------------------------
// r8 skeleton (best measured): 256x128 tile, BK=128 (= one quant group),
// 512 thr / 8 waves, LDS double-buffer with stage(g+1)-before-compute(g),
// G4 XOR swizzle both sides, exact int32 MFMA + fp32 rescale.
// v13 adds T5: s_setprio(1) around the MFMA+rescale cluster -- the two
// phase-independent blocks/CU give the scheduler a role split (staging vs
// computing) that priority can arbitrate.
// ---------------------------------------------------------------------------

// gu LDS map (bytes): buf b at b*65536: A@0 (32K), BG@32768 (16K), BU@49152.
// scales @131072 + b*2048: sSa(1024) sSg@+1024(512) sSu@+1536(512).
// rmx@135168 (2048), rs@137216 (1024). Total 138240.
#define GU_SC 131072
#define GU_RMX 135168
#define GU_RS 137216
#define GU_LDS 138240

// Fused gate/up GEMM + SwiGLU + hidden group-quant (group = tile's 128 cols).
__global__ __launch_bounds__(512, 2)
void gemm_gu_i8(const char* __restrict__ Aq, const char* __restrict__ Bg,
                const char* __restrict__ Bu,
                const float* __restrict__ sAT, const float* __restrict__ sGT,
                const float* __restrict__ sUT,
                char* __restrict__ Hq, float* __restrict__ sHT,
                int M, int N, int K, int NBN) {
  extern __shared__ __align__(16) char smem[];
  const int tid = threadIdx.x;
  const int lane = tid & 63;
  const int wid = tid >> 6;
  const int wm = wid >> 1, wn = wid & 1;
  const int wr = wm * 64, wc = wn * 64;
  const int l15 = lane & 15, l16 = lane >> 4;

  const int nwg = gridDim.x;
  const int wg = ((int)blockIdx.x & 7) * (nwg >> 3) + ((int)blockIdx.x >> 3);
  const long m0 = (long)(wg / NBN) * 256;
  const long n0 = (long)(wg % NBN) * 128;

  // staging: chunk c = tid + 512k -> row = (tid>>3) + 64k, swizzled col.
  const long rowS = tid >> 3;
  const int offS = ((tid & 7) * 16) ^ ((int)(rowS & 7) << 4);
  const long kstr = 64L * K;
  const char* gA0 = Aq + (m0 + rowS) * K + offS;   // k = 0..3
  const char* gG0 = Bg + (n0 + rowS) * K + offS;   // k = 0..1
  const char* gU0 = Bu + (n0 + rowS) * K + offS;

  const int rdSwz = (l15 & 7) << 4;
  const int colK0 = (l16 * 16) ^ rdSwz;
  const int colK1 = (64 + l16 * 16) ^ rdSwz;

  f32x4 accg[4][4], accu[4][4];
#pragma unroll
  for (int i = 0; i < 4; i++)
#pragma unroll
    for (int j = 0; j < 4; j++) {
      accg[i][j] = (f32x4){0.f, 0.f, 0.f, 0.f};
      accu[i][j] = (f32x4){0.f, 0.f, 0.f, 0.f};
    }
  const i32x4 iz = {0, 0, 0, 0};
  const int KG = K >> 7;

#define GU_STAGE(gg, bb)                                                      \
  {                                                                           \
    const long kb = (long)(gg) << 7;                                          \
    char* tb = smem + (bb) * 65536;                                           \
    _Pragma("unroll") for (int k = 0; k < 4; k++)                             \
        gl_lds16(gA0 + kb + k * kstr, tb + (tid + 512 * k) * 16);             \
    _Pragma("unroll") for (int k = 0; k < 2; k++) {                           \
      gl_lds16(gG0 + kb + k * kstr, tb + 32768 + (tid + 512 * k) * 16);       \
      gl_lds16(gU0 + kb + k * kstr, tb + 49152 + (tid + 512 * k) * 16);       \
    }                                                                         \
    char* sc = smem + GU_SC + (bb) * 2048;                                    \
    if (wid < 4) {                                                            \
      gl_lds4(sAT + (long)(gg) * M + m0 + tid, sc + wid * 256);               \
    } else if (wid < 6) {                                                     \
      gl_lds4(sGT + (long)(gg) * N + n0 + (tid - 256), sc + 1024 + (wid - 4) * 256); \
    } else {                                                                  \
      gl_lds4(sUT + (long)(gg) * N + n0 + (tid - 384), sc + 1536 + (wid - 6) * 256); \
    }                                                                         \
  }

  GU_STAGE(0, 0);
  __syncthreads();

  for (int g = 0; g < KG; ++g) {
    const int cb = g & 1;
    if (g + 1 < KG) GU_STAGE(g + 1, cb ^ 1);

    const char* tb = smem + cb * 65536;
    const float* sc = (const float*)(smem + GU_SC + cb * 2048);

    i32x4 af[4][2];
#pragma unroll
    for (int i = 0; i < 4; i++) {
      const int rb = (wr + i * 16 + l15) * 128;
      af[i][0] = *(const i32x4*)(tb + rb + colK0);
      af[i][1] = *(const i32x4*)(tb + rb + colK1);
    }
    f32x4 sa4[4];
#pragma unroll
    for (int i = 0; i < 4; i++)
      sa4[i] = *(const f32x4*)(sc + wr + i * 16 + l16 * 4);

    __builtin_amdgcn_s_setprio(1);
#pragma unroll
    for (int j = 0; j < 4; j++) {
      const int rbB = (wc + j * 16 + l15) * 128;
      i32x4 bgf[2], buf_[2];
      bgf[0] = *(const i32x4*)(tb + 32768 + rbB + colK0);
      bgf[1] = *(const i32x4*)(tb + 32768 + rbB + colK1);
      buf_[0] = *(const i32x4*)(tb + 49152 + rbB + colK0);
      buf_[1] = *(const i32x4*)(tb + 49152 + rbB + colK1);
      float sbg = sc[256 + wc + j * 16 + l15];
      float sbu = sc[384 + wc + j * 16 + l15];
#pragma unroll
      for (int i = 0; i < 4; i++) {
        i32x4 tg = __builtin_amdgcn_mfma_i32_16x16x64_i8(af[i][0], bgf[0], iz, 0, 0, 0);
        tg = __builtin_amdgcn_mfma_i32_16x16x64_i8(af[i][1], bgf[1], tg, 0, 0, 0);
        i32x4 tu = __builtin_amdgcn_mfma_i32_16x16x64_i8(af[i][0], buf_[0], iz, 0, 0, 0);
        tu = __builtin_amdgcn_mfma_i32_16x16x64_i8(af[i][1], buf_[1], tu, 0, 0, 0);
        f32x4 mg = sa4[i] * sbg;
        f32x4 mu = sa4[i] * sbu;
        accg[i][j] += mg * __builtin_convertvector(tg, f32x4);
        accu[i][j] += mu * __builtin_convertvector(tu, f32x4);
      }
    }
    __builtin_amdgcn_s_setprio(0);
    __syncthreads();  // drains vmcnt: stage(g+1) resident; all reads of cb done
  }

  // ---- epilogue: h = silu(g)*u; per-row (128-col group) max -> s; quantize.
  float* rmx = (float*)(smem + GU_RMX);  // [2][256]
  float* rs = (float*)(smem + GU_RS);    // [256]
  float pm[4][4];
#pragma unroll
  for (int i = 0; i < 4; i++)
#pragma unroll
    for (int r = 0; r < 4; r++) pm[i][r] = 0.f;
#pragma unroll
  for (int i = 0; i < 4; i++)
#pragma unroll
    for (int j = 0; j < 4; j++)
#pragma unroll
      for (int r = 0; r < 4; r++) {
        float gv = accg[i][j][r];
        float h = gv / (1.f + expf(-gv)) * accu[i][j][r];
        accu[i][j][r] = h;
        pm[i][r] = fmaxf(pm[i][r], fabsf(h));
      }
#pragma unroll
  for (int i = 0; i < 4; i++)
#pragma unroll
    for (int r = 0; r < 4; r++) {
      pm[i][r] = fmaxf(pm[i][r], __shfl_xor(pm[i][r], 1));
      pm[i][r] = fmaxf(pm[i][r], __shfl_xor(pm[i][r], 2));
      pm[i][r] = fmaxf(pm[i][r], __shfl_xor(pm[i][r], 4));
      pm[i][r] = fmaxf(pm[i][r], __shfl_xor(pm[i][r], 8));
    }
#pragma unroll
  for (int i = 0; i < 4; i++)
#pragma unroll
    for (int r = 0; r < 4; r++)
      if (l15 == i * 4 + r) rmx[wn * 256 + wr + i * 16 + l16 * 4 + r] = pm[i][r];
  __syncthreads();
  if (tid < 256) {
    float mx = fmaxf(rmx[tid], rmx[256 + tid]);
    float s = fmaxf(mx / QMAXF, EPSQ);
    rs[tid] = s;
    sHT[(n0 >> 7) * (long)M + m0 + tid] = s;
  }
  __syncthreads();
  // quantize into buf0-A region (K-loop done), then coalesced copy out
  char* sQ = smem;  // 256 rows x 128 B
#pragma unroll
  for (int i = 0; i < 4; i++) {
    f32x4 sr = *(const f32x4*)(rs + wr + i * 16 + l16 * 4);
#pragma unroll
    for (int j = 0; j < 4; j++)
#pragma unroll
      for (int r = 0; r < 4; r++) {
        float qv = fminf(fmaxf(rintf(accu[i][j][r] / sr[r]), -QMAXF), QMAXF);
        sQ[(wr + i * 16 + l16 * 4 + r) * 128 + wc + j * 16 + l15] = (char)(int)qv;
      }
  }
  __syncthreads();
  {
    int row = tid >> 1, seg = tid & 1;
    const i32x4* src = (const i32x4*)(sQ + row * 128 + seg * 64);
    i32x4* dst = (i32x4*)(Hq + (m0 + row) * N + n0 + seg * 64);
#pragma unroll
    for (int k = 0; k < 4; k++) dst[k] = src[k];
  }
}

// dn LDS map: buf b at b*49152: A@0 (32K), B@32768 (16K).
// scales @98304 + b*1536: sSa(1024) sSb@+1024(512). Total 101376.
#define DN_SC 98304
#define DN_LDS 101376

// Down GEMM: fp32 out = dequant(A_i8) . dequant(B_i8)^T with exact int cores.
__global__ __launch_bounds__(512, 2)
void gemm_dn_i8(const char* __restrict__ Aq, const char* __restrict__ Bq,
                const float* __restrict__ sAT, const float* __restrict__ sBT,
                float* __restrict__ C, int M, int N, int K, int NBN) {
  extern __shared__ __align__(16) char smem[];
  const int tid = threadIdx.x;
  const int lane = tid & 63;
  const int wid = tid >> 6;
  const int wm = wid >> 1, wn = wid & 1;
  const int wr = wm * 64, wc = wn * 64;
  const int l15 = lane & 15, l16 = lane >> 4;

  const int nwg = gridDim.x;
  const int wg = ((int)blockIdx.x & 7) * (nwg >> 3) + ((int)blockIdx.x >> 3);
  const long m0 = (long)(wg / NBN) * 256;
  const long n0 = (long)(wg % NBN) * 128;

  const long rowS = tid >> 3;
  const int offS = ((tid & 7) * 16) ^ ((int)(rowS & 7) << 4);
  const long kstr = 64L * K;
  const char* gA0 = Aq + (m0 + rowS) * K + offS;
  const char* gB0 = Bq + (n0 + rowS) * K + offS;

  const int rdSwz = (l15 & 7) << 4;
  const int colK0 = (l16 * 16) ^ rdSwz;
  const int colK1 = (64 + l16 * 16) ^ rdSwz;

  f32x4 acc[4][4];
#pragma unroll
  for (int i = 0; i < 4; i++)
#pragma unroll
    for (int j = 0; j < 4; j++) acc[i][j] = (f32x4){0.f, 0.f, 0.f, 0.f};
  const i32x4 iz = {0, 0, 0, 0};
  const int KG = K >> 7;

#define DN_STAGE(gg, bb)                                                      \
  {                                                                           \
    const long kb = (long)(gg) << 7;                                          \
    char* tb = smem + (bb) * 49152;                                           \
    _Pragma("unroll") for (int k = 0; k < 4; k++)                             \
        gl_lds16(gA0 + kb + k * kstr, tb + (tid + 512 * k) * 16);             \
    _Pragma("unroll") for (int k = 0; k < 2; k++)                             \
        gl_lds16(gB0 + kb + k * kstr, tb + 32768 + (tid + 512 * k) * 16);     \
    char* sc = smem + DN_SC + (bb) * 1536;                                    \
    if (wid < 4) {                                                            \
      gl_lds4(sAT + (long)(gg) * M + m0 + tid, sc + wid * 256);               \
    } else if (wid < 6) {                                                     \
      gl_lds4(sBT + (long)(gg) * N + n0 + (tid - 256), sc + 1024 + (wid - 4) * 256); \
    }                                                                         \
  }

  DN_STAGE(0, 0);
  __syncthreads();

  for (int g = 0; g < KG; ++g) {
    const int cb = g & 1;
    if (g + 1 < KG) DN_STAGE(g + 1, cb ^ 1);

    const char* tb = smem + cb * 49152;
    const float* sc = (const float*)(smem + DN_SC + cb * 1536);

    i32x4 af[4][2];
#pragma unroll
    for (int i = 0; i < 4; i++) {
      const int rb = (wr + i * 16 + l15) * 128;
      af[i][0] = *(const i32x4*)(tb + rb + colK0);
      af[i][1] = *(const i32x4*)(tb + rb + colK1);
    }
    f32x4 sa4[4];
#pragma unroll
    for (int i = 0; i < 4; i++)
      sa4[i] = *(const f32x4*)(sc + wr + i * 16 + l16 * 4);

    __builtin_amdgcn_s_setprio(1);
#pragma unroll
    for (int j = 0; j < 4; j++) {
      const int rbB = (wc + j * 16 + l15) * 128;
      i32x4 bf[2];
      bf[0] = *(const i32x4*)(tb + 32768 + rbB + colK0);
      bf[1] = *(const i32x4*)(tb + 32768 + rbB + colK1);
      float sb = sc[256 + wc + j * 16 + l15];
#pragma unroll
      for (int i = 0; i < 4; i++) {
        i32x4 t = __builtin_amdgcn_mfma_i32_16x16x64_i8(af[i][0], bf[0], iz, 0, 0, 0);
        t = __builtin_amdgcn_mfma_i32_16x16x64_i8(af[i][1], bf[1], t, 0, 0, 0);
        f32x4 ms = sa4[i] * sb;
        acc[i][j] += ms * __builtin_convertvector(t, f32x4);
      }
    }
    __builtin_amdgcn_s_setprio(0);
    __syncthreads();
  }

#pragma unroll
  for (int i = 0; i < 4; i++)
#pragma unroll
    for (int j = 0; j < 4; j++)
#pragma unroll
      for (int r = 0; r < 4; r++) {
        long row = m0 + wr + i * 16 + l16 * 4 + r;
        long col = n0 + wc + j * 16 + l15;
        C[row * N + col] = acc[i][j][r];
      }
}

extern "C" void kernel_launch(void* const* d_in, const int* in_sizes, int n_in,
                              void* d_out, int out_size, void* d_ws, size_t ws_size,
                              hipStream_t stream) {
  (void)n_in; (void)out_size;
  const float* x  = (const float*)d_in[0];
  const float* wg = (const float*)d_in[1];
  const float* wu = (const float*)d_in[2];
  const float* wd = (const float*)d_in[3];
  float* out = (float*)d_out;

  const long H = 4096;
  const long M = in_sizes[0] / H;   // 4096 (B*S)
  const long I = in_sizes[1] / H;   // 11008
  const long GH = H >> 7;           // 32
  const long GI = I >> 7;           // 86

  char* ws = (char*)d_ws;
  size_t off = 0;
  char* xq  = ws + off; off += (size_t)(M * H);
  char* wgq = ws + off; off += (size_t)(I * H);
  char* wuq = ws + off; off += (size_t)(I * H);
  char* wdq = ws + off; off += (size_t)(H * I);
  char* hq  = ws + off; off += (size_t)(M * I);
  float* s_x = (float*)(ws + off); off += (size_t)(GH * M) * 4;
  float* s_g = (float*)(ws + off); off += (size_t)(GH * I) * 4;
  float* s_u = (float*)(ws + off); off += (size_t)(GH * I) * 4;
  float* s_d = (float*)(ws + off); off += (size_t)(GI * H) * 4;
  float* s_h = (float*)(ws + off); off += (size_t)(GI * M) * 4;
  if (ws_size < off) return;

  hipFuncSetAttribute((const void*)gemm_gu_i8,
                      hipFuncAttributeMaxDynamicSharedMemorySize, GU_LDS);
  hipFuncSetAttribute((const void*)gemm_dn_i8,
                      hipFuncAttributeMaxDynamicSharedMemorySize, DN_LDS);

  // 1) int8 group-quant of inputs/weights (q + transposed scales)
  {
    long ng;
    ng = M * H / 128;
    qdq8<<<dim3((unsigned)((ng + 7) / 8)), dim3(256), 0, stream>>>(x, xq, s_x, ng, (int)GH, (int)M);
    ng = I * H / 128;
    qdq8<<<dim3((unsigned)((ng + 7) / 8)), dim3(256), 0, stream>>>(wg, wgq, s_g, ng, (int)GH, (int)I);
    qdq8<<<dim3((unsigned)((ng + 7) / 8)), dim3(256), 0, stream>>>(wu, wuq, s_u, ng, (int)GH, (int)I);
    ng = H * I / 128;
    qdq8<<<dim3((unsigned)((ng + 7) / 8)), dim3(256), 0, stream>>>(wd, wdq, s_d, ng, (int)GI, (int)H);
  }

  // 2) fused gate/up int8 GEMM + SwiGLU + hidden quant -> hq, s_h
  {
    const int NBN = (int)GI;                       // 86
    const int grid = (int)(M / 256) * NBN;         // 1376 (%8==0)
    gemm_gu_i8<<<dim3(grid), dim3(512), GU_LDS, stream>>>(
        xq, wgq, wuq, s_x, s_g, s_u, hq, s_h, (int)M, (int)I, (int)H, NBN);
  }
  // 3) down int8 GEMM -> fp32 out
  {
    const int NBN = (int)GH;                       // 32
    const int grid = (int)(M / 256) * NBN;         // 512 (%8==0)
    gemm_dn_i8<<<dim3(grid), dim3(512), DN_LDS, stream>>>(
        hq, wdq, s_h, s_d, out, (int)M, (int)H, (int)I, NBN);
  }
}

// Round 14
// 1061.927 us; speedup vs baseline: 2.9829x; 1.0078x over previous
//
#include <hip/hip_runtime.h>
#include <math.h>

typedef int i32x4 __attribute__((ext_vector_type(4)));
typedef float f32x4 __attribute__((ext_vector_type(4)));
typedef float f32x2 __attribute__((ext_vector_type(2)));

#define QMAXF 127.0f
#define EPSQ 1e-8f

__device__ __forceinline__ void gl_lds16(const void* g, void* l) {
  __builtin_amdgcn_global_load_lds(
      (const __attribute__((address_space(1))) unsigned int*)g,
      (__attribute__((address_space(3))) unsigned int*)l, 16, 0, 0);
}
__device__ __forceinline__ void gl_lds4(const void* g, void* l) {
  __builtin_amdgcn_global_load_lds(
      (const __attribute__((address_space(1))) unsigned int*)g,
      (__attribute__((address_space(3))) unsigned int*)l, 4, 0, 0);
}

// Group-of-128 symmetric int8 quant: fp32 in -> int8 q + transposed scales.
// Exact reference math in fp32; f32x4 loads, group per 32-lane half-wave (r13).
__global__ __launch_bounds__(256)
void qdq8(const float* __restrict__ in, char* __restrict__ q,
          float* __restrict__ sT, long n_groups, int gpr, int R) {
  long grp = (long)blockIdx.x * 8 + (threadIdx.x >> 5);
  if (grp >= n_groups) return;
  int hl = threadIdx.x & 31;
  long base = grp * 128 + hl * 4;
  f32x4 v = *(const f32x4*)(in + base);
  float m = fmaxf(fmaxf(fabsf(v.x), fabsf(v.y)), fmaxf(fabsf(v.z), fabsf(v.w)));
#pragma unroll
  for (int off = 16; off; off >>= 1) m = fmaxf(m, __shfl_xor(m, off));
  float s = fmaxf(m / QMAXF, EPSQ);
  int q0 = (int)fminf(fmaxf(rintf(v.x / s), -QMAXF), QMAXF);
  int q1 = (int)fminf(fmaxf(rintf(v.y / s), -QMAXF), QMAXF);
  int q2 = (int)fminf(fmaxf(rintf(v.z / s), -QMAXF), QMAXF);
  int q3 = (int)fminf(fmaxf(rintf(v.w / s), -QMAXF), QMAXF);
  *(int*)(q + base) = (q0 & 0xff) | ((q1 & 0xff) << 8) |
                      ((q2 & 0xff) << 16) | ((q3 & 0xff) << 24);
  if (hl == 0) {
    long row = grp / gpr;
    long gc = grp - row * gpr;
    sT[gc * (long)R + row] = s;
  }
}

// ---------------------------------------------------------------------------
// r8/r13 skeleton (best measured): 256x128 tile, BK=128 (= one quant group),
// 512 thr / 8 waves, LDS double-buffer (stage(g+1) before compute(g)),
// G4 XOR swizzle both sides, exact int32 MFMA + fp32 rescale.
// v14: depth-1 software pipeline at the (i,j) step -- current step's MFMAs
// (into tgP/tuP temps) overlap the PREVIOUS step's cvt+fma rescale (the two
// are independent), so the MFMA and VALU pipes run concurrently instead of
// alternating in dependent bursts. Fully unrolled => prev indices are
// compile-time (rule #20). Only 16 extra live regs (r11's 64-reg version
// spilled; this must keep VGPR=128, WRITE_SIZE ~45MB).
// ---------------------------------------------------------------------------

// gu LDS map (bytes): buf b at b*65536: A@0 (32K), BG@32768 (16K), BU@49152.
// scales @131072 + b*2048: sSa(1024) sSg@+1024(512) sSu@+1536(512).
// rmx@135168 (2048), rs@137216 (1024). Total 138240.
#define GU_SC 131072
#define GU_RMX 135168
#define GU_RS 137216
#define GU_LDS 138240

// Fused gate/up GEMM + SwiGLU + hidden group-quant (group = tile's 128 cols).
__global__ __launch_bounds__(512, 2)
void gemm_gu_i8(const char* __restrict__ Aq, const char* __restrict__ Bg,
                const char* __restrict__ Bu,
                const float* __restrict__ sAT, const float* __restrict__ sGT,
                const float* __restrict__ sUT,
                char* __restrict__ Hq, float* __restrict__ sHT,
                int M, int N, int K, int NBN) {
  extern __shared__ __align__(16) char smem[];
  const int tid = threadIdx.x;
  const int lane = tid & 63;
  const int wid = tid >> 6;
  const int wm = wid >> 1, wn = wid & 1;
  const int wr = wm * 64, wc = wn * 64;
  const int l15 = lane & 15, l16 = lane >> 4;

  const int nwg = gridDim.x;
  const int wg = ((int)blockIdx.x & 7) * (nwg >> 3) + ((int)blockIdx.x >> 3);
  const long m0 = (long)(wg / NBN) * 256;
  const long n0 = (long)(wg % NBN) * 128;

  const long rowS = tid >> 3;
  const int offS = ((tid & 7) * 16) ^ ((int)(rowS & 7) << 4);
  const long kstr = 64L * K;
  const char* gA0 = Aq + (m0 + rowS) * K + offS;   // k = 0..3
  const char* gG0 = Bg + (n0 + rowS) * K + offS;   // k = 0..1
  const char* gU0 = Bu + (n0 + rowS) * K + offS;

  const int rdSwz = (l15 & 7) << 4;
  const int colK0 = (l16 * 16) ^ rdSwz;
  const int colK1 = (64 + l16 * 16) ^ rdSwz;

  f32x4 accg[4][4], accu[4][4];
#pragma unroll
  for (int i = 0; i < 4; i++)
#pragma unroll
    for (int j = 0; j < 4; j++) {
      accg[i][j] = (f32x4){0.f, 0.f, 0.f, 0.f};
      accu[i][j] = (f32x4){0.f, 0.f, 0.f, 0.f};
    }
  const i32x4 iz = {0, 0, 0, 0};
  const int KG = K >> 7;

#define GU_STAGE(gg, bb)                                                      \
  {                                                                           \
    const long kb = (long)(gg) << 7;                                          \
    char* tb = smem + (bb) * 65536;                                           \
    _Pragma("unroll") for (int k = 0; k < 4; k++)                             \
        gl_lds16(gA0 + kb + k * kstr, tb + (tid + 512 * k) * 16);             \
    _Pragma("unroll") for (int k = 0; k < 2; k++) {                           \
      gl_lds16(gG0 + kb + k * kstr, tb + 32768 + (tid + 512 * k) * 16);       \
      gl_lds16(gU0 + kb + k * kstr, tb + 49152 + (tid + 512 * k) * 16);       \
    }                                                                         \
    char* sc = smem + GU_SC + (bb) * 2048;                                    \
    if (wid < 4) {                                                            \
      gl_lds4(sAT + (long)(gg) * M + m0 + tid, sc + wid * 256);               \
    } else if (wid < 6) {                                                     \
      gl_lds4(sGT + (long)(gg) * N + n0 + (tid - 256), sc + 1024 + (wid - 4) * 256); \
    } else {                                                                  \
      gl_lds4(sUT + (long)(gg) * N + n0 + (tid - 384), sc + 1536 + (wid - 6) * 256); \
    }                                                                         \
  }

  GU_STAGE(0, 0);
  __syncthreads();

  for (int g = 0; g < KG; ++g) {
    const int cb = g & 1;
    if (g + 1 < KG) GU_STAGE(g + 1, cb ^ 1);

    const char* tb = smem + cb * 65536;
    const float* sc = (const float*)(smem + GU_SC + cb * 2048);

    i32x4 af[4][2];
#pragma unroll
    for (int i = 0; i < 4; i++) {
      const int rb = (wr + i * 16 + l15) * 128;
      af[i][0] = *(const i32x4*)(tb + rb + colK0);
      af[i][1] = *(const i32x4*)(tb + rb + colK1);
    }
    f32x4 sa4[4];
#pragma unroll
    for (int i = 0; i < 4; i++)
      sa4[i] = *(const f32x4*)(sc + wr + i * 16 + l16 * 4);

    // depth-1 pipelined (j,i) loop: MFMAs of step s overlap rescale of s-1
    i32x4 tgP, tuP;
    f32x4 mgP, muP;
#pragma unroll
    for (int j = 0; j < 4; j++) {
      const int rbB = (wc + j * 16 + l15) * 128;
      i32x4 bgf0 = *(const i32x4*)(tb + 32768 + rbB + colK0);
      i32x4 bgf1 = *(const i32x4*)(tb + 32768 + rbB + colK1);
      i32x4 buf0 = *(const i32x4*)(tb + 49152 + rbB + colK0);
      i32x4 buf1 = *(const i32x4*)(tb + 49152 + rbB + colK1);
      float sbg = sc[256 + wc + j * 16 + l15];
      float sbu = sc[384 + wc + j * 16 + l15];
#pragma unroll
      for (int i = 0; i < 4; i++) {
        i32x4 tg = __builtin_amdgcn_mfma_i32_16x16x64_i8(af[i][0], bgf0, iz, 0, 0, 0);
        tg = __builtin_amdgcn_mfma_i32_16x16x64_i8(af[i][1], bgf1, tg, 0, 0, 0);
        i32x4 tu = __builtin_amdgcn_mfma_i32_16x16x64_i8(af[i][0], buf0, iz, 0, 0, 0);
        tu = __builtin_amdgcn_mfma_i32_16x16x64_i8(af[i][1], buf1, tu, 0, 0, 0);
        if (j > 0 || i > 0) {
          const int pf = j * 4 + i - 1;
          const int ip = pf & 3, jp = pf >> 2;
          accg[ip][jp] += mgP * __builtin_convertvector(tgP, f32x4);
          accu[ip][jp] += muP * __builtin_convertvector(tuP, f32x4);
        }
        tgP = tg; tuP = tu;
        mgP = sa4[i] * sbg; muP = sa4[i] * sbu;
      }
    }
    accg[3][3] += mgP * __builtin_convertvector(tgP, f32x4);
    accu[3][3] += muP * __builtin_convertvector(tuP, f32x4);
    __syncthreads();  // drains vmcnt: stage(g+1) resident; all reads of cb done
  }

  // ---- epilogue: h = silu(g)*u; per-row (128-col group) max -> s; quantize.
  float* rmx = (float*)(smem + GU_RMX);  // [2][256]
  float* rs = (float*)(smem + GU_RS);    // [256]
  float pm[4][4];
#pragma unroll
  for (int i = 0; i < 4; i++)
#pragma unroll
    for (int r = 0; r < 4; r++) pm[i][r] = 0.f;
#pragma unroll
  for (int i = 0; i < 4; i++)
#pragma unroll
    for (int j = 0; j < 4; j++)
#pragma unroll
      for (int r = 0; r < 4; r++) {
        float gv = accg[i][j][r];
        float h = gv / (1.f + expf(-gv)) * accu[i][j][r];
        accu[i][j][r] = h;
        pm[i][r] = fmaxf(pm[i][r], fabsf(h));
      }
#pragma unroll
  for (int i = 0; i < 4; i++)
#pragma unroll
    for (int r = 0; r < 4; r++) {
      pm[i][r] = fmaxf(pm[i][r], __shfl_xor(pm[i][r], 1));
      pm[i][r] = fmaxf(pm[i][r], __shfl_xor(pm[i][r], 2));
      pm[i][r] = fmaxf(pm[i][r], __shfl_xor(pm[i][r], 4));
      pm[i][r] = fmaxf(pm[i][r], __shfl_xor(pm[i][r], 8));
    }
#pragma unroll
  for (int i = 0; i < 4; i++)
#pragma unroll
    for (int r = 0; r < 4; r++)
      if (l15 == i * 4 + r) rmx[wn * 256 + wr + i * 16 + l16 * 4 + r] = pm[i][r];
  __syncthreads();
  if (tid < 256) {
    float mx = fmaxf(rmx[tid], rmx[256 + tid]);
    float s = fmaxf(mx / QMAXF, EPSQ);
    rs[tid] = s;
    sHT[(n0 >> 7) * (long)M + m0 + tid] = s;
  }
  __syncthreads();
  char* sQ = smem;  // 256 rows x 128 B
#pragma unroll
  for (int i = 0; i < 4; i++) {
    f32x4 sr = *(const f32x4*)(rs + wr + i * 16 + l16 * 4);
#pragma unroll
    for (int j = 0; j < 4; j++)
#pragma unroll
      for (int r = 0; r < 4; r++) {
        float qv = fminf(fmaxf(rintf(accu[i][j][r] / sr[r]), -QMAXF), QMAXF);
        sQ[(wr + i * 16 + l16 * 4 + r) * 128 + wc + j * 16 + l15] = (char)(int)qv;
      }
  }
  __syncthreads();
  {
    int row = tid >> 1, seg = tid & 1;
    const i32x4* src = (const i32x4*)(sQ + row * 128 + seg * 64);
    i32x4* dst = (i32x4*)(Hq + (m0 + row) * N + n0 + seg * 64);
#pragma unroll
    for (int k = 0; k < 4; k++) dst[k] = src[k];
  }
}

// dn LDS map: buf b at b*49152: A@0 (32K), B@32768 (16K).
// scales @98304 + b*1536: sSa(1024) sSb@+1024(512). Total 101376.
#define DN_SC 98304
#define DN_LDS 101376

// Down GEMM: fp32 out = dequant(A_i8) . dequant(B_i8)^T with exact int cores.
__global__ __launch_bounds__(512, 2)
void gemm_dn_i8(const char* __restrict__ Aq, const char* __restrict__ Bq,
                const float* __restrict__ sAT, const float* __restrict__ sBT,
                float* __restrict__ C, int M, int N, int K, int NBN) {
  extern __shared__ __align__(16) char smem[];
  const int tid = threadIdx.x;
  const int lane = tid & 63;
  const int wid = tid >> 6;
  const int wm = wid >> 1, wn = wid & 1;
  const int wr = wm * 64, wc = wn * 64;
  const int l15 = lane & 15, l16 = lane >> 4;

  const int nwg = gridDim.x;
  const int wg = ((int)blockIdx.x & 7) * (nwg >> 3) + ((int)blockIdx.x >> 3);
  const long m0 = (long)(wg / NBN) * 256;
  const long n0 = (long)(wg % NBN) * 128;

  const long rowS = tid >> 3;
  const int offS = ((tid & 7) * 16) ^ ((int)(rowS & 7) << 4);
  const long kstr = 64L * K;
  const char* gA0 = Aq + (m0 + rowS) * K + offS;
  const char* gB0 = Bq + (n0 + rowS) * K + offS;

  const int rdSwz = (l15 & 7) << 4;
  const int colK0 = (l16 * 16) ^ rdSwz;
  const int colK1 = (64 + l16 * 16) ^ rdSwz;

  f32x4 acc[4][4];
#pragma unroll
  for (int i = 0; i < 4; i++)
#pragma unroll
    for (int j = 0; j < 4; j++) acc[i][j] = (f32x4){0.f, 0.f, 0.f, 0.f};
  const i32x4 iz = {0, 0, 0, 0};
  const int KG = K >> 7;

#define DN_STAGE(gg, bb)                                                      \
  {                                                                           \
    const long kb = (long)(gg) << 7;                                          \
    char* tb = smem + (bb) * 49152;                                           \
    _Pragma("unroll") for (int k = 0; k < 4; k++)                             \
        gl_lds16(gA0 + kb + k * kstr, tb + (tid + 512 * k) * 16);             \
    _Pragma("unroll") for (int k = 0; k < 2; k++)                             \
        gl_lds16(gB0 + kb + k * kstr, tb + 32768 + (tid + 512 * k) * 16);     \
    char* sc = smem + DN_SC + (bb) * 1536;                                    \
    if (wid < 4) {                                                            \
      gl_lds4(sAT + (long)(gg) * M + m0 + tid, sc + wid * 256);               \
    } else if (wid < 6) {                                                     \
      gl_lds4(sBT + (long)(gg) * N + n0 + (tid - 256), sc + 1024 + (wid - 4) * 256); \
    }                                                                         \
  }

  DN_STAGE(0, 0);
  __syncthreads();

  for (int g = 0; g < KG; ++g) {
    const int cb = g & 1;
    if (g + 1 < KG) DN_STAGE(g + 1, cb ^ 1);

    const char* tb = smem + cb * 49152;
    const float* sc = (const float*)(smem + DN_SC + cb * 1536);

    i32x4 af[4][2];
#pragma unroll
    for (int i = 0; i < 4; i++) {
      const int rb = (wr + i * 16 + l15) * 128;
      af[i][0] = *(const i32x4*)(tb + rb + colK0);
      af[i][1] = *(const i32x4*)(tb + rb + colK1);
    }
    f32x4 sa4[4];
#pragma unroll
    for (int i = 0; i < 4; i++)
      sa4[i] = *(const f32x4*)(sc + wr + i * 16 + l16 * 4);

    i32x4 tP;
    f32x4 msP;
#pragma unroll
    for (int j = 0; j < 4; j++) {
      const int rbB = (wc + j * 16 + l15) * 128;
      i32x4 bf0 = *(const i32x4*)(tb + 32768 + rbB + colK0);
      i32x4 bf1 = *(const i32x4*)(tb + 32768 + rbB + colK1);
      float sb = sc[256 + wc + j * 16 + l15];
#pragma unroll
      for (int i = 0; i < 4; i++) {
        i32x4 t = __builtin_amdgcn_mfma_i32_16x16x64_i8(af[i][0], bf0, iz, 0, 0, 0);
        t = __builtin_amdgcn_mfma_i32_16x16x64_i8(af[i][1], bf1, t, 0, 0, 0);
        if (j > 0 || i > 0) {
          const int pf = j * 4 + i - 1;
          const int ip = pf & 3, jp = pf >> 2;
          acc[ip][jp] += msP * __builtin_convertvector(tP, f32x4);
        }
        tP = t;
        msP = sa4[i] * sb;
      }
    }
    acc[3][3] += msP * __builtin_convertvector(tP, f32x4);
    __syncthreads();
  }

#pragma unroll
  for (int i = 0; i < 4; i++)
#pragma unroll
    for (int j = 0; j < 4; j++)
#pragma unroll
      for (int r = 0; r < 4; r++) {
        long row = m0 + wr + i * 16 + l16 * 4 + r;
        long col = n0 + wc + j * 16 + l15;
        C[row * N + col] = acc[i][j][r];
      }
}

extern "C" void kernel_launch(void* const* d_in, const int* in_sizes, int n_in,
                              void* d_out, int out_size, void* d_ws, size_t ws_size,
                              hipStream_t stream) {
  (void)n_in; (void)out_size;
  const float* x  = (const float*)d_in[0];
  const float* wg = (const float*)d_in[1];
  const float* wu = (const float*)d_in[2];
  const float* wd = (const float*)d_in[3];
  float* out = (float*)d_out;

  const long H = 4096;
  const long M = in_sizes[0] / H;   // 4096 (B*S)
  const long I = in_sizes[1] / H;   // 11008
  const long GH = H >> 7;           // 32
  const long GI = I >> 7;           // 86

  char* ws = (char*)d_ws;
  size_t off = 0;
  char* xq  = ws + off; off += (size_t)(M * H);
  char* wgq = ws + off; off += (size_t)(I * H);
  char* wuq = ws + off; off += (size_t)(I * H);
  char* wdq = ws + off; off += (size_t)(H * I);
  char* hq  = ws + off; off += (size_t)(M * I);
  float* s_x = (float*)(ws + off); off += (size_t)(GH * M) * 4;
  float* s_g = (float*)(ws + off); off += (size_t)(GH * I) * 4;
  float* s_u = (float*)(ws + off); off += (size_t)(GH * I) * 4;
  float* s_d = (float*)(ws + off); off += (size_t)(GI * H) * 4;
  float* s_h = (float*)(ws + off); off += (size_t)(GI * M) * 4;
  if (ws_size < off) return;

  hipFuncSetAttribute((const void*)gemm_gu_i8,
                      hipFuncAttributeMaxDynamicSharedMemorySize, GU_LDS);
  hipFuncSetAttribute((const void*)gemm_dn_i8,
                      hipFuncAttributeMaxDynamicSharedMemorySize, DN_LDS);

  // 1) int8 group-quant of inputs/weights (q + transposed scales)
  {
    long ng;
    ng = M * H / 128;
    qdq8<<<dim3((unsigned)((ng + 7) / 8)), dim3(256), 0, stream>>>(x, xq, s_x, ng, (int)GH, (int)M);
    ng = I * H / 128;
    qdq8<<<dim3((unsigned)((ng + 7) / 8)), dim3(256), 0, stream>>>(wg, wgq, s_g, ng, (int)GH, (int)I);
    qdq8<<<dim3((unsigned)((ng + 7) / 8)), dim3(256), 0, stream>>>(wu, wuq, s_u, ng, (int)GH, (int)I);
    ng = H * I / 128;
    qdq8<<<dim3((unsigned)((ng + 7) / 8)), dim3(256), 0, stream>>>(wd, wdq, s_d, ng, (int)GI, (int)H);
  }

  // 2) fused gate/up int8 GEMM + SwiGLU + hidden quant -> hq, s_h
  {
    const int NBN = (int)GI;                       // 86
    const int grid = (int)(M / 256) * NBN;         // 1376 (%8==0)
    gemm_gu_i8<<<dim3(grid), dim3(512), GU_LDS, stream>>>(
        xq, wgq, wuq, s_x, s_g, s_u, hq, s_h, (int)M, (int)I, (int)H, NBN);
  }
  // 3) down int8 GEMM -> fp32 out
  {
    const int NBN = (int)GH;                       // 32
    const int grid = (int)(M / 256) * NBN;         // 512 (%8==0)
    gemm_dn_i8<<<dim3(grid), dim3(512), DN_LDS, stream>>>(
        hq, wdq, s_h, s_d, out, (int)M, (int)H, (int)I, NBN);
  }
}